// Round 6
// baseline (663.046 us; speedup 1.0000x reference)
//
#include <hip/hip_runtime.h>
#include <stdint.h>

#define FEAT_IN 128
#define F1 32
#define F2 64
#define FJ 96
#define FH 128

#define BSH 8                  // 256 nodes per bucket
#define BNODES 256
#define NBMAX 512              // supports up to 512 buckets (131072 nodes)
#define CH 8192                // edges per scatter block
#define SRCBITS 17             // nN must be < 2^17 (100000 ok)
#define SRCMASK 0x1FFFFu

__device__ __forceinline__ unsigned f2bf(float f) {
    unsigned u = __float_as_uint(f);
    return (u + 0x7FFFu + ((u >> 16) & 1u)) >> 16;   // RNE
}
__device__ __forceinline__ float bf2f(unsigned h) {
    return __uint_as_float(h << 16);
}
__device__ __forceinline__ void bfacc8(float* a, uint4 v) {
    a[0] += bf2f(v.x & 0xffffu); a[1] += bf2f(v.x >> 16);
    a[2] += bf2f(v.y & 0xffffu); a[3] += bf2f(v.y >> 16);
    a[4] += bf2f(v.z & 0xffffu); a[5] += bf2f(v.z >> 16);
    a[6] += bf2f(v.w & 0xffffu); a[7] += bf2f(v.w >> 16);
}

// ---------- bucket histogram ----------
__global__ void histA(const int* __restrict__ dst, int* __restrict__ bcnt, int nE, int nB) {
    __shared__ int h[NBMAX];
    for (int t = threadIdx.x; t < nB; t += blockDim.x) h[t] = 0;
    __syncthreads();
    int stride = gridDim.x * blockDim.x;
    for (int e = blockIdx.x * blockDim.x + threadIdx.x; e < nE; e += stride)
        atomicAdd(&h[dst[e] >> BSH], 1);
    __syncthreads();
    for (int t = threadIdx.x; t < nB; t += blockDim.x)
        if (h[t]) atomicAdd(&bcnt[t], h[t]);
}

// ---------- scan buckets (single block) ----------
__global__ void scanBk(const int* __restrict__ bcnt, int* __restrict__ boff,
                       int* __restrict__ bcur, int nB, int nE) {
    __shared__ int ps[256];
    int t = threadIdx.x;
    int c[4]; int s = 0;
#pragma unroll
    for (int k = 0; k < 4; ++k) { int b = t * 4 + k; c[k] = (b < nB) ? bcnt[b] : 0; s += c[k]; }
    ps[t] = s; __syncthreads();
    for (int off = 1; off < 256; off <<= 1) {
        int v = (t >= off) ? ps[t - off] : 0; __syncthreads();
        ps[t] += v; __syncthreads();
    }
    int excl = ps[t] - s;
#pragma unroll
    for (int k = 0; k < 4; ++k) {
        int b = t * 4 + k;
        if (b < nB) { boff[b] = excl; bcur[b] = excl; excl += c[k]; }
    }
    if (t == 255) boff[nB] = nE;
}

// ---------- scatter edges into buckets, LDS-staged ----------
__global__ void scatterEB(const int* __restrict__ src, const int* __restrict__ dst,
                          int* __restrict__ bcur, unsigned* __restrict__ EB, int nE, int nB) {
    __shared__ int h[NBMAX], loff[NBMAX], gbase[NBMAX], lcur[NBMAX];
    __shared__ int ps[256];
    __shared__ uint2 stage[CH];
    int t = threadIdx.x;
    int e0 = blockIdx.x * CH;
    int ecnt = min(CH, nE - e0);
    if (ecnt <= 0) return;
    for (int i = t; i < nB; i += 256) h[i] = 0;
    __syncthreads();
    for (int i = t; i < ecnt; i += 256) atomicAdd(&h[dst[e0 + i] >> BSH], 1);
    __syncthreads();
    int b0 = 2 * t, b1 = 2 * t + 1;
    int c0 = (b0 < nB) ? h[b0] : 0;
    int c1 = (b1 < nB) ? h[b1] : 0;
    ps[t] = c0 + c1; __syncthreads();
    for (int off = 1; off < 256; off <<= 1) {
        int v = (t >= off) ? ps[t - off] : 0; __syncthreads();
        ps[t] += v; __syncthreads();
    }
    int excl = ps[t] - (c0 + c1);
    if (b0 < nB) { loff[b0] = excl;      lcur[b0] = excl; }
    if (b1 < nB) { loff[b1] = excl + c0; lcur[b1] = excl + c0; }
    __syncthreads();
    for (int i = t; i < nB; i += 256)
        if (h[i]) gbase[i] = atomicAdd(&bcur[i], h[i]);
    __syncthreads();
    for (int i = t; i < ecnt; i += 256) {
        int d = dst[e0 + i], s = src[e0 + i];
        int b = d >> BSH;
        int p = atomicAdd(&lcur[b], 1);
        stage[p] = make_uint2((unsigned)s, (unsigned)d);
    }
    __syncthreads();
    for (int i = t; i < ecnt; i += 256) {
        uint2 v = stage[i];
        int bb = (int)(v.y >> BSH);
        EB[gbase[bb] + (i - loff[bb])] = v.x | ((v.y & (BNODES - 1)) << SRCBITS);
    }
}

// ---------- per-bucket counting sort -> csr, rowptr, dinv ----------
__global__ void __launch_bounds__(256)
bucketSortK(const unsigned* __restrict__ EB, const int* __restrict__ boff,
            int* __restrict__ rowptr, int* __restrict__ csr, float* __restrict__ dinv,
            int nN, int nE, int nB) {
    __shared__ int hist[BNODES];
    __shared__ int cur[BNODES];
    __shared__ int ps[256];
    int b = blockIdx.x, t = threadIdx.x;
    int beg = boff[b], end = boff[b + 1];
    hist[t] = 0;
    __syncthreads();
    for (int i = beg + t; i < end; i += 256) atomicAdd(&hist[EB[i] >> SRCBITS], 1);
    __syncthreads();
    int deg = hist[t];
    ps[t] = deg; __syncthreads();
    for (int off = 1; off < 256; off <<= 1) {
        int v = (t >= off) ? ps[t - off] : 0; __syncthreads();
        ps[t] += v; __syncthreads();
    }
    int excl = beg + ps[t] - deg;
    int node = (b << BSH) + t;
    if (node < nN) {
        rowptr[node] = excl;
        dinv[node] = rsqrtf((float)deg + 1.0f);
    }
    cur[t] = excl;
    if (b == nB - 1 && t == 0) rowptr[nN] = nE;
    __syncthreads();
    for (int i = beg + t; i < end; i += 256) {
        unsigned v = EB[i];
        int p = atomicAdd(&cur[v >> SRCBITS], 1);
        csr[p] = (int)(v & SRCMASK);
    }
}

// ---------- g1 = bf16((x @ W1) * dinv) ----------
__global__ void gemm1_kernel(const float4* __restrict__ x4, const float* __restrict__ W1,
                             const float* __restrict__ dinv, unsigned* __restrict__ G16,
                             int nN) {
    __shared__ float Ws[FEAT_IN * F1];
    __shared__ float xs[8][FEAT_IN];
    for (int t = threadIdx.x; t < FEAT_IN * F1; t += 256) Ws[t] = W1[t];
    int rb = blockIdx.x * 8;
    {
        int r = threadIdx.x >> 5, c = threadIdx.x & 31;
        int row = rb + r;
        float4 v = (row < nN) ? x4[(size_t)row * 32 + c] : make_float4(0, 0, 0, 0);
        ((float4*)xs[r])[c] = v;
    }
    __syncthreads();
    int r = threadIdx.x >> 5;
    int row = rb + r;
    if (row >= nN) return;
    int j = threadIdx.x & 31;
    float acc = 0.f;
#pragma unroll 8
    for (int k = 0; k < FEAT_IN; ++k) acc = fmaf(xs[r][k], Ws[k * F1 + j], acc);
    float g = acc * dinv[row];
    float other = __shfl_xor(g, 1);
    if ((j & 1) == 0)
        G16[(size_t)row * 16 + (j >> 1)] = f2bf(g) | (f2bf(other) << 16);
}

// ---------- agg1: wave/node, 16 slots x uint4(8 bf16), 32 edges in flight ----------
__global__ void agg1_kernel(const int* __restrict__ rowptr, const int* __restrict__ csr,
                            const uint4* __restrict__ G16, const float* __restrict__ dinv,
                            const float* __restrict__ b1, const int* __restrict__ batch,
                            uint4* __restrict__ H16, float* __restrict__ psum, int nN) {
    int node = blockIdx.x * 4 + (threadIdx.x >> 6);
    if (node >= nN) return;
    int lane = threadIdx.x & 63;
    int slot = lane >> 2;      // 0..15
    int comp = lane & 3;       // uint4 index within 64B row
    int beg = rowptr[node], end = rowptr[node + 1];
    float a[8] = {0, 0, 0, 0, 0, 0, 0, 0};
    int e = beg + slot;
    for (; e + 16 < end; e += 32) {
        int s0 = csr[e], s1 = csr[e + 16];
        uint4 v0 = G16[(size_t)s0 * 4 + comp];
        uint4 v1 = G16[(size_t)s1 * 4 + comp];
        bfacc8(a, v0);
        bfacc8(a, v1);
    }
    if (e < end) {
        int s = csr[e];
        bfacc8(a, G16[(size_t)s * 4 + comp]);
    }
#pragma unroll
    for (int m = 4; m < 64; m <<= 1) {
#pragma unroll
        for (int i = 0; i < 8; ++i) a[i] += __shfl_xor(a[i], m);
    }
    if (slot == 0) {
        bfacc8(a, G16[(size_t)node * 4 + comp]);   // self-loop
        float dv = dinv[node];
        const float* bb = b1 + comp * 8;
        float x1[8];
        float h[8];
#pragma unroll
        for (int i = 0; i < 8; ++i) {
            float v = fmaf(dv, a[i], bb[i]);
            x1[i] = v > 0.f ? v : 0.f;
            h[i] = dv * x1[i];
        }
        uint4 hp;
        hp.x = f2bf(h[0]) | (f2bf(h[1]) << 16);
        hp.y = f2bf(h[2]) | (f2bf(h[3]) << 16);
        hp.z = f2bf(h[4]) | (f2bf(h[5]) << 16);
        hp.w = f2bf(h[6]) | (f2bf(h[7]) << 16);
        H16[(size_t)node * 4 + comp] = hp;
        int bg = batch[node];
        float* ps = psum + (size_t)bg * FJ + comp * 8;
#pragma unroll
        for (int i = 0; i < 8; ++i) atomicAdd(ps + i, x1[i]);
    }
}

// ---------- agg2: gather H16, fused 32->64 GEMM + relu + pool ----------
__global__ void agg2_kernel(const int* __restrict__ rowptr, const int* __restrict__ csr,
                            const uint4* __restrict__ H16, const float* __restrict__ dinv,
                            const float* __restrict__ W2, const float* __restrict__ b2,
                            const int* __restrict__ batch, float* __restrict__ psum, int nN) {
    __shared__ float W2s[F1 * F2];
    __shared__ float aLds[4][F1];
    for (int t = threadIdx.x; t < F1 * F2; t += blockDim.x) W2s[t] = W2[t];
    int wv = threadIdx.x >> 6;
    int node = blockIdx.x * 4 + wv;
    int lane = threadIdx.x & 63;
    bool valid = node < nN;
    int slot = lane >> 2, comp = lane & 3;
    float a[8] = {0, 0, 0, 0, 0, 0, 0, 0};
    if (valid) {
        int beg = rowptr[node], end = rowptr[node + 1];
        int e = beg + slot;
        for (; e + 16 < end; e += 32) {
            int s0 = csr[e], s1 = csr[e + 16];
            uint4 v0 = H16[(size_t)s0 * 4 + comp];
            uint4 v1 = H16[(size_t)s1 * 4 + comp];
            bfacc8(a, v0);
            bfacc8(a, v1);
        }
        if (e < end) {
            int s = csr[e];
            bfacc8(a, H16[(size_t)s * 4 + comp]);
        }
    }
#pragma unroll
    for (int m = 4; m < 64; m <<= 1) {
#pragma unroll
        for (int i = 0; i < 8; ++i) a[i] += __shfl_xor(a[i], m);
    }
    if (valid && slot == 0) {
        bfacc8(a, H16[(size_t)node * 4 + comp]);   // self-loop
#pragma unroll
        for (int i = 0; i < 8; ++i) aLds[wv][comp * 8 + i] = a[i];
    }
    __syncthreads();
    if (valid) {
        int j = lane;
        const float* ar = aLds[wv];
        float dot = 0.f;
#pragma unroll
        for (int k = 0; k < F1; ++k) dot = fmaf(ar[k], W2s[k * F2 + j], dot);
        float v = fmaf(dinv[node], dot, b2[j]);
        float x2 = fmaxf(v, 0.f);
        int bg = batch[node];
        atomicAdd(&psum[(size_t)bg * FJ + F1 + j], x2);
    }
}

__global__ void cnt_kernel(const int* __restrict__ batch, float* __restrict__ cnt, int nN) {
    int i = blockIdx.x * blockDim.x + threadIdx.x;
    if (i < nN) atomicAdd(&cnt[batch[i]], 1.0f);
}

__global__ void mlp_kernel(const float* __restrict__ psum, const float* __restrict__ cnt,
                           const float* __restrict__ fW1, const float* __restrict__ fb1,
                           const float* __restrict__ fW2, const float* __restrict__ fb2,
                           float* __restrict__ out) {
    __shared__ float p[FJ];
    __shared__ float red[FH];
    int g = blockIdx.x, tid = threadIdx.x;
    float c = fmaxf(cnt[g], 1.0f);
    if (tid < FJ) p[tid] = psum[g * FJ + tid] / c;
    __syncthreads();
    float acc = fb1[tid];
    for (int k = 0; k < FJ; ++k) acc = fmaf(p[k], fW1[k * FH + tid], acc);
    float h = fmaxf(acc, 0.f);
    red[tid] = h * fW2[tid];
    __syncthreads();
    for (int s = FH / 2; s > 0; s >>= 1) {
        if (tid < s) red[tid] += red[tid + s];
        __syncthreads();
    }
    if (tid == 0) out[g] = red[0] + fb2[0];
}

extern "C" void kernel_launch(void* const* d_in, const int* in_sizes, int n_in,
                              void* d_out, int out_size, void* d_ws, size_t ws_size,
                              hipStream_t stream) {
    const float* x   = (const float*)d_in[0];
    const int*   ei  = (const int*)d_in[1];
    const int*   bat = (const int*)d_in[2];
    const float* W1  = (const float*)d_in[3];
    const float* b1  = (const float*)d_in[4];
    const float* W2  = (const float*)d_in[5];
    const float* b2  = (const float*)d_in[6];
    const float* fW1 = (const float*)d_in[7];
    const float* fb1 = (const float*)d_in[8];
    const float* fW2 = (const float*)d_in[9];
    const float* fb2 = (const float*)d_in[10];
    float* out = (float*)d_out;

    int nN = in_sizes[0] / FEAT_IN;
    int nE = in_sizes[1] / 2;
    int nG = out_size;
    const int* src = ei;
    const int* dst = ei + nE;

    int nB  = (nN + BNODES - 1) >> BSH;
    int nCh = (nE + CH - 1) / CH;

    char* w = (char*)d_ws;
    auto alloc = [&](size_t bytes) { char* p = w; w += (bytes + 15) & ~(size_t)15; return p; };
    int*      bcnt   = (int*)alloc(NBMAX * 4);
    int*      boff   = (int*)alloc((NBMAX + 1) * 4);
    int*      bcur   = (int*)alloc(NBMAX * 4);
    unsigned* EB     = (unsigned*)alloc((size_t)nE * 4);
    int*      rowptr = (int*)alloc((size_t)(nN + 1) * 4);
    int*      csr    = (int*)alloc((size_t)nE * 4);
    float*    dinv   = (float*)alloc((size_t)nN * 4);
    unsigned* G16    = (unsigned*)alloc((size_t)nN * F1 * 2);
    unsigned* H16    = (unsigned*)alloc((size_t)nN * F1 * 2);
    float*    psum   = (float*)alloc((size_t)nG * FJ * 4);
    float*    cnt    = (float*)alloc((size_t)nG * 4);

    hipMemsetAsync(bcnt, 0, NBMAX * 4, stream);
    hipMemsetAsync(psum, 0, (size_t)nG * FJ * 4, stream);
    hipMemsetAsync(cnt, 0, (size_t)nG * 4, stream);

    // CSR build via dst-buckets
    histA<<<1024, 256, 0, stream>>>(dst, bcnt, nE, nB);
    scanBk<<<1, 256, 0, stream>>>(bcnt, boff, bcur, nB, nE);
    scatterEB<<<nCh, 256, 0, stream>>>(src, dst, bcur, EB, nE, nB);
    bucketSortK<<<nB, 256, 0, stream>>>(EB, boff, rowptr, csr, dinv, nN, nE, nB);

    // layer 1: transform -> aggregate (+pool x1, +H for layer 2)
    gemm1_kernel<<<(nN + 7) / 8, 256, 0, stream>>>((const float4*)x, W1, dinv, G16, nN);
    agg1_kernel<<<(nN + 3) / 4, 256, 0, stream>>>(rowptr, csr, (const uint4*)G16, dinv, b1, bat,
                                                  (uint4*)H16, psum, nN);
    // layer 2: aggregate (32-dim bf16) -> transform (+pool x2)
    agg2_kernel<<<(nN + 3) / 4, 256, 0, stream>>>(rowptr, csr, (const uint4*)H16, dinv, W2, b2,
                                                  bat, psum, nN);

    cnt_kernel<<<(nN + 255) / 256, 256, 0, stream>>>(bat, cnt, nN);
    mlp_kernel<<<nG, FH, 0, stream>>>(psum, cnt, fW1, fb1, fW2, fb2, out);
}

// Round 8
// 580.362 us; speedup vs baseline: 1.1425x; 1.1425x over previous
//
#include <hip/hip_runtime.h>
#include <stdint.h>

#define FEAT_IN 128
#define F1 32
#define F2 64
#define FJ 96
#define FH 128

#define BSH 8                  // 256 nodes per bucket
#define BNODES 256
#define NBMAX 512
#define CH 8192
#define SRCBITS 17             // nN must be < 2^17
#define SRCMASK 0x1FFFFu
#define NCHUNK 4
#define CF 8                   // features per chunk (32 B rows)

// ---------- bucket histogram ----------
__global__ void histA(const int* __restrict__ dst, int* __restrict__ bcnt, int nE, int nB) {
    __shared__ int h[NBMAX];
    for (int t = threadIdx.x; t < nB; t += blockDim.x) h[t] = 0;
    __syncthreads();
    int stride = gridDim.x * blockDim.x;
    for (int e = blockIdx.x * blockDim.x + threadIdx.x; e < nE; e += stride)
        atomicAdd(&h[dst[e] >> BSH], 1);
    __syncthreads();
    for (int t = threadIdx.x; t < nB; t += blockDim.x)
        if (h[t]) atomicAdd(&bcnt[t], h[t]);
}

// ---------- scan buckets ----------
__global__ void scanBk(const int* __restrict__ bcnt, int* __restrict__ boff,
                       int* __restrict__ bcur, int nB, int nE) {
    __shared__ int ps[256];
    int t = threadIdx.x;
    int c[4]; int s = 0;
#pragma unroll
    for (int k = 0; k < 4; ++k) { int b = t * 4 + k; c[k] = (b < nB) ? bcnt[b] : 0; s += c[k]; }
    ps[t] = s; __syncthreads();
    for (int off = 1; off < 256; off <<= 1) {
        int v = (t >= off) ? ps[t - off] : 0; __syncthreads();
        ps[t] += v; __syncthreads();
    }
    int excl = ps[t] - s;
#pragma unroll
    for (int k = 0; k < 4; ++k) {
        int b = t * 4 + k;
        if (b < nB) { boff[b] = excl; bcur[b] = excl; excl += c[k]; }
    }
    if (t == 255) boff[nB] = nE;
}

// ---------- scatter edges into buckets, LDS-staged ----------
__global__ void scatterEB(const int* __restrict__ src, const int* __restrict__ dst,
                          int* __restrict__ bcur, unsigned* __restrict__ EB, int nE, int nB) {
    __shared__ int h[NBMAX], loff[NBMAX], gbase[NBMAX], lcur[NBMAX];
    __shared__ int ps[256];
    __shared__ uint2 stage[CH];
    int t = threadIdx.x;
    int e0 = blockIdx.x * CH;
    int ecnt = min(CH, nE - e0);
    if (ecnt <= 0) return;
    for (int i = t; i < nB; i += 256) h[i] = 0;
    __syncthreads();
    for (int i = t; i < ecnt; i += 256) atomicAdd(&h[dst[e0 + i] >> BSH], 1);
    __syncthreads();
    int b0 = 2 * t, b1 = 2 * t + 1;
    int c0 = (b0 < nB) ? h[b0] : 0;
    int c1 = (b1 < nB) ? h[b1] : 0;
    ps[t] = c0 + c1; __syncthreads();
    for (int off = 1; off < 256; off <<= 1) {
        int v = (t >= off) ? ps[t - off] : 0; __syncthreads();
        ps[t] += v; __syncthreads();
    }
    int excl = ps[t] - (c0 + c1);
    if (b0 < nB) { loff[b0] = excl;      lcur[b0] = excl; }
    if (b1 < nB) { loff[b1] = excl + c0; lcur[b1] = excl + c0; }
    __syncthreads();
    for (int i = t; i < nB; i += 256)
        if (h[i]) gbase[i] = atomicAdd(&bcur[i], h[i]);
    __syncthreads();
    for (int i = t; i < ecnt; i += 256) {
        int d = dst[e0 + i], s = src[e0 + i];
        int b = d >> BSH;
        int p = atomicAdd(&lcur[b], 1);
        stage[p] = make_uint2((unsigned)s, (unsigned)d);
    }
    __syncthreads();
    for (int i = t; i < ecnt; i += 256) {
        uint2 v = stage[i];
        int bb = (int)(v.y >> BSH);
        EB[gbase[bb] + (i - loff[bb])] = v.x | ((v.y & (BNODES - 1)) << SRCBITS);
    }
}

// ---------- per-bucket counting sort -> csr, rowptr, dinv ----------
__global__ void __launch_bounds__(256)
bucketSortK(const unsigned* __restrict__ EB, const int* __restrict__ boff,
            int* __restrict__ rowptr, int* __restrict__ csr, float* __restrict__ dinv,
            int nN, int nE, int nB) {
    __shared__ int hist[BNODES];
    __shared__ int cur[BNODES];
    __shared__ int ps[256];
    int b = blockIdx.x, t = threadIdx.x;
    int beg = boff[b], end = boff[b + 1];
    hist[t] = 0;
    __syncthreads();
    for (int i = beg + t; i < end; i += 256) atomicAdd(&hist[EB[i] >> SRCBITS], 1);
    __syncthreads();
    int deg = hist[t];
    ps[t] = deg; __syncthreads();
    for (int off = 1; off < 256; off <<= 1) {
        int v = (t >= off) ? ps[t - off] : 0; __syncthreads();
        ps[t] += v; __syncthreads();
    }
    int excl = beg + ps[t] - deg;
    int node = (b << BSH) + t;
    if (node < nN) {
        rowptr[node] = excl;
        dinv[node] = rsqrtf((float)deg + 1.0f);
    }
    cur[t] = excl;
    if (b == nB - 1 && t == 0) rowptr[nN] = nE;
    __syncthreads();
    for (int i = beg + t; i < end; i += 256) {
        unsigned v = EB[i];
        int p = atomicAdd(&cur[v >> SRCBITS], 1);
        csr[p] = (int)(v & SRCMASK);
    }
}

// ---------- g1 = (x @ W1) * dinv, CHUNKED output: Gc[c][node][8] ----------
__global__ void gemm1_kernel(const float4* __restrict__ x4, const float* __restrict__ W1,
                             const float* __restrict__ dinv, float* __restrict__ Gc, int nN) {
    __shared__ float Ws[FEAT_IN * F1];
    __shared__ float xs[8][FEAT_IN];
    for (int t = threadIdx.x; t < FEAT_IN * F1; t += 256) Ws[t] = W1[t];
    int rb = blockIdx.x * 8;
    {
        int r = threadIdx.x >> 5, c = threadIdx.x & 31;
        int row = rb + r;
        float4 v = (row < nN) ? x4[(size_t)row * 32 + c] : make_float4(0, 0, 0, 0);
        ((float4*)xs[r])[c] = v;
    }
    __syncthreads();
    int r = threadIdx.x >> 5;
    int row = rb + r;
    if (row >= nN) return;
    int j = threadIdx.x & 31;
    float acc = 0.f;
#pragma unroll 8
    for (int k = 0; k < FEAT_IN; ++k) acc = fmaf(xs[r][k], Ws[k * F1 + j], acc);
    float g = acc * dinv[row];
    Gc[(size_t)(j >> 3) * nN * CF + (size_t)row * CF + (j & 7)] = g;
}

// ---------- chunked aggregation core: 32 slots x 2 lanes x float4 ----------
__device__ __forceinline__ float4 gatherChunk(const int* __restrict__ rowptr,
                                              const int* __restrict__ csr,
                                              const float* __restrict__ Gchunk,
                                              int node, int slot, int comp) {
    int beg = rowptr[node], end = rowptr[node + 1];
    float4 a = make_float4(0.f, 0.f, 0.f, 0.f);
    int e = beg + slot;
    for (; e + 32 < end; e += 64) {
        int s0 = csr[e], s1 = csr[e + 32];
        float4 g0 = *(const float4*)(Gchunk + (size_t)s0 * CF + comp * 4);
        float4 g1 = *(const float4*)(Gchunk + (size_t)s1 * CF + comp * 4);
        a.x += g0.x + g1.x; a.y += g0.y + g1.y;
        a.z += g0.z + g1.z; a.w += g0.w + g1.w;
    }
    if (e < end) {
        float4 g = *(const float4*)(Gchunk + (size_t)csr[e] * CF + comp * 4);
        a.x += g.x; a.y += g.y; a.z += g.z; a.w += g.w;
        e += 32;
        if (e < end) {
            float4 g2 = *(const float4*)(Gchunk + (size_t)csr[e] * CF + comp * 4);
            a.x += g2.x; a.y += g2.y; a.z += g2.z; a.w += g2.w;
        }
    }
    // reduce across 32 slots (bit 0 = comp is preserved)
#pragma unroll
    for (int m = 2; m < 64; m <<= 1) {
        a.x += __shfl_xor(a.x, m);
        a.y += __shfl_xor(a.y, m);
        a.z += __shfl_xor(a.z, m);
        a.w += __shfl_xor(a.w, m);
    }
    return a;
}

// lanes 0..7 receive feature f=lane. After reduce: even lanes hold f0-3 in
// a.xyzw, odd lanes hold f4-7. Shuffle ALL components from the src lane,
// select with the DESTINATION's sel (fix for R7's __shfl semantics bug).
__device__ __forceinline__ float redistribute8(float4 a, int lane) {
    int src = (lane >> 2) & 1;
    float vx = __shfl(a.x, src);
    float vy = __shfl(a.y, src);
    float vz = __shfl(a.z, src);
    float vw = __shfl(a.w, src);
    int sel = lane & 3;
    return (sel == 0) ? vx : (sel == 1) ? vy : (sel == 2) ? vz : vw;
}

// ---------- agg1 (chunked, XCD-pinned): x1 chunk -> psum, H chunk ----------
__global__ void agg1c(const int* __restrict__ rowptr, const int* __restrict__ csr,
                      const float* __restrict__ Gc, const float* __restrict__ dinv,
                      const float* __restrict__ b1, const int* __restrict__ batch,
                      float* __restrict__ Hc, float* __restrict__ psum, int nN, int K) {
    int b = blockIdx.x;
    int xcd = b & 7;
    int c = xcd & 3;
    int k = (b >> 3) * 2 + (xcd >> 2);
    if (k >= K) return;
    int node = k * 4 + (threadIdx.x >> 6);
    if (node >= nN) return;
    int lane = threadIdx.x & 63;
    const float* Gchunk = Gc + (size_t)c * nN * CF;
    float4 a = gatherChunk(rowptr, csr, Gchunk, node, lane >> 1, lane & 1);
    float v = redistribute8(a, lane);
    if (lane < CF) {
        float accf = v + Gchunk[(size_t)node * CF + lane];  // self-loop
        float dv = dinv[node];
        float x1 = fmaxf(fmaf(dv, accf, b1[c * CF + lane]), 0.f);
        Hc[(size_t)c * nN * CF + (size_t)node * CF + lane] = dv * x1;
        atomicAdd(&psum[(size_t)batch[node] * FJ + c * CF + lane], x1);
    }
}

// ---------- agg2 (chunked, XCD-pinned): A2 chunk = dinv * agg(H) ----------
__global__ void agg2c(const int* __restrict__ rowptr, const int* __restrict__ csr,
                      const float* __restrict__ Hc, const float* __restrict__ dinv,
                      float* __restrict__ A2, int nN, int K) {
    int b = blockIdx.x;
    int xcd = b & 7;
    int c = xcd & 3;
    int k = (b >> 3) * 2 + (xcd >> 2);
    if (k >= K) return;
    int node = k * 4 + (threadIdx.x >> 6);
    if (node >= nN) return;
    int lane = threadIdx.x & 63;
    const float* Hchunk = Hc + (size_t)c * nN * CF;
    float4 a = gatherChunk(rowptr, csr, Hchunk, node, lane >> 1, lane & 1);
    float v = redistribute8(a, lane);
    if (lane < CF) {
        float accf = v + Hchunk[(size_t)node * CF + lane];  // self-loop
        A2[(size_t)node * F1 + c * CF + lane] = dinv[node] * accf;
    }
}

// ---------- x2 = relu(A2 @ W2 + b2), fused pool ----------
__global__ void gemm2pool(const float* __restrict__ A2, const float* __restrict__ W2,
                          const float* __restrict__ b2, const int* __restrict__ batch,
                          float* __restrict__ psum, int nN) {
    __shared__ float W2s[F1 * F2];
    __shared__ float aL[4][F1];
    for (int t = threadIdx.x; t < F1 * F2; t += 256) W2s[t] = W2[t];
    int wv = threadIdx.x >> 6, lane = threadIdx.x & 63;
    int node = blockIdx.x * 4 + wv;
    if (node < nN && lane < F1) aL[wv][lane] = A2[(size_t)node * F1 + lane];
    __syncthreads();
    if (node >= nN) return;
    float dot = 0.f;
#pragma unroll
    for (int kk = 0; kk < F1; ++kk) dot = fmaf(aL[wv][kk], W2s[kk * F2 + lane], dot);
    float x2 = fmaxf(dot + b2[lane], 0.f);
    atomicAdd(&psum[(size_t)batch[node] * FJ + F1 + lane], x2);
}

__global__ void cnt_kernel(const int* __restrict__ batch, float* __restrict__ cnt, int nN) {
    int i = blockIdx.x * blockDim.x + threadIdx.x;
    if (i < nN) atomicAdd(&cnt[batch[i]], 1.0f);
}

__global__ void mlp_kernel(const float* __restrict__ psum, const float* __restrict__ cnt,
                           const float* __restrict__ fW1, const float* __restrict__ fb1,
                           const float* __restrict__ fW2, const float* __restrict__ fb2,
                           float* __restrict__ out) {
    __shared__ float p[FJ];
    __shared__ float red[FH];
    int g = blockIdx.x, tid = threadIdx.x;
    float c = fmaxf(cnt[g], 1.0f);
    if (tid < FJ) p[tid] = psum[g * FJ + tid] / c;
    __syncthreads();
    float acc = fb1[tid];
    for (int k = 0; k < FJ; ++k) acc = fmaf(p[k], fW1[k * FH + tid], acc);
    float h = fmaxf(acc, 0.f);
    red[tid] = h * fW2[tid];
    __syncthreads();
    for (int s = FH / 2; s > 0; s >>= 1) {
        if (tid < s) red[tid] += red[tid + s];
        __syncthreads();
    }
    if (tid == 0) out[g] = red[0] + fb2[0];
}

extern "C" void kernel_launch(void* const* d_in, const int* in_sizes, int n_in,
                              void* d_out, int out_size, void* d_ws, size_t ws_size,
                              hipStream_t stream) {
    const float* x   = (const float*)d_in[0];
    const int*   ei  = (const int*)d_in[1];
    const int*   bat = (const int*)d_in[2];
    const float* W1  = (const float*)d_in[3];
    const float* b1  = (const float*)d_in[4];
    const float* W2  = (const float*)d_in[5];
    const float* b2  = (const float*)d_in[6];
    const float* fW1 = (const float*)d_in[7];
    const float* fb1 = (const float*)d_in[8];
    const float* fW2 = (const float*)d_in[9];
    const float* fb2 = (const float*)d_in[10];
    float* out = (float*)d_out;

    int nN = in_sizes[0] / FEAT_IN;
    int nE = in_sizes[1] / 2;
    int nG = out_size;
    const int* src = ei;
    const int* dst = ei + nE;

    int nB  = (nN + BNODES - 1) >> BSH;
    int nCh = (nE + CH - 1) / CH;
    int K   = (nN + 3) / 4;           // node-groups of 4 (one per wave)
    int gridC = ((K + 1) / 2) * 8;    // XCD-pinned chunk grid

    char* w = (char*)d_ws;
    auto alloc = [&](size_t bytes) { char* p = w; w += (bytes + 15) & ~(size_t)15; return p; };
    int*      bcnt   = (int*)alloc(NBMAX * 4);
    int*      boff   = (int*)alloc((NBMAX + 1) * 4);
    int*      bcur   = (int*)alloc(NBMAX * 4);
    unsigned* EB     = (unsigned*)alloc((size_t)nE * 4);
    int*      rowptr = (int*)alloc((size_t)(nN + 1) * 4);
    int*      csr    = (int*)alloc((size_t)nE * 4);
    float*    dinv   = (float*)alloc((size_t)nN * 4);
    float*    Gc     = (float*)alloc((size_t)nN * F1 * 4);   // chunked [4][nN][8]
    float*    Hc     = (float*)alloc((size_t)nN * F1 * 4);   // chunked [4][nN][8]
    float*    A2     = (float*)alloc((size_t)nN * F1 * 4);   // [nN][32]
    float*    psum   = (float*)alloc((size_t)nG * FJ * 4);
    float*    cnt    = (float*)alloc((size_t)nG * 4);

    hipMemsetAsync(bcnt, 0, NBMAX * 4, stream);
    hipMemsetAsync(psum, 0, (size_t)nG * FJ * 4, stream);
    hipMemsetAsync(cnt, 0, (size_t)nG * 4, stream);

    // CSR build via dst-buckets
    histA<<<1024, 256, 0, stream>>>(dst, bcnt, nE, nB);
    scanBk<<<1, 256, 0, stream>>>(bcnt, boff, bcur, nB, nE);
    scatterEB<<<nCh, 256, 0, stream>>>(src, dst, bcur, EB, nE, nB);
    bucketSortK<<<nB, 256, 0, stream>>>(EB, boff, rowptr, csr, dinv, nN, nE, nB);

    // layer 1
    gemm1_kernel<<<(nN + 7) / 8, 256, 0, stream>>>((const float4*)x, W1, dinv, Gc, nN);
    agg1c<<<gridC, 256, 0, stream>>>(rowptr, csr, Gc, dinv, b1, bat, Hc, psum, nN, K);
    // layer 2
    agg2c<<<gridC, 256, 0, stream>>>(rowptr, csr, Hc, dinv, A2, nN, K);
    gemm2pool<<<(nN + 3) / 4, 256, 0, stream>>>(A2, W2, b2, bat, psum, nN);

    cnt_kernel<<<(nN + 255) / 256, 256, 0, stream>>>(bat, cnt, nN);
    mlp_kernel<<<nG, FH, 0, stream>>>(psum, cnt, fW1, fb1, fW2, fb2, out);
}

// Round 9
// 508.494 us; speedup vs baseline: 1.3039x; 1.1413x over previous
//
#include <hip/hip_runtime.h>
#include <stdint.h>

#define FEAT_IN 128
#define F1 32
#define F2 64
#define FJ 96
#define FH 128

#define BSH 8                  // 256 nodes per bucket
#define BNODES 256
#define NBMAX 512
#define CH 8192
#define SRCBITS 17             // nN must be < 2^17
#define SRCMASK 0x1FFFFu
#define PADMAX 768             // max pad per bucket (256 nodes * 3)

__device__ __forceinline__ unsigned f2bf(float f) {
    unsigned u = __float_as_uint(f);
    return (u + 0x7FFFu + ((u >> 16) & 1u)) >> 16;   // RNE
}
__device__ __forceinline__ float bf2f(unsigned h) { return __uint_as_float(h << 16); }
__device__ __forceinline__ void bfacc8(float* a, uint4 v) {
    a[0] += bf2f(v.x & 0xffffu); a[1] += bf2f(v.x >> 16);
    a[2] += bf2f(v.y & 0xffffu); a[3] += bf2f(v.y >> 16);
    a[4] += bf2f(v.z & 0xffffu); a[5] += bf2f(v.z >> 16);
    a[6] += bf2f(v.w & 0xffffu); a[7] += bf2f(v.w >> 16);
}

// ---------- bucket histogram ----------
__global__ void histA(const int* __restrict__ dst, int* __restrict__ bcnt, int nE, int nB) {
    __shared__ int h[NBMAX];
    for (int t = threadIdx.x; t < nB; t += blockDim.x) h[t] = 0;
    __syncthreads();
    int stride = gridDim.x * blockDim.x;
    for (int e = blockIdx.x * blockDim.x + threadIdx.x; e < nE; e += stride)
        atomicAdd(&h[dst[e] >> BSH], 1);
    __syncthreads();
    for (int t = threadIdx.x; t < nB; t += blockDim.x)
        if (h[t]) atomicAdd(&bcnt[t], h[t]);
}

// ---------- scan buckets ----------
__global__ void scanBk(const int* __restrict__ bcnt, int* __restrict__ boff,
                       int* __restrict__ bcur, int nB, int nE) {
    __shared__ int ps[256];
    int t = threadIdx.x;
    int c[4]; int s = 0;
#pragma unroll
    for (int k = 0; k < 4; ++k) { int b = t * 4 + k; c[k] = (b < nB) ? bcnt[b] : 0; s += c[k]; }
    ps[t] = s; __syncthreads();
    for (int off = 1; off < 256; off <<= 1) {
        int v = (t >= off) ? ps[t - off] : 0; __syncthreads();
        ps[t] += v; __syncthreads();
    }
    int excl = ps[t] - s;
#pragma unroll
    for (int k = 0; k < 4; ++k) {
        int b = t * 4 + k;
        if (b < nB) { boff[b] = excl; bcur[b] = excl; excl += c[k]; }
    }
    if (t == 255) boff[nB] = nE;
}

// ---------- scatter edges into buckets, LDS-staged ----------
__global__ void scatterEB(const int* __restrict__ src, const int* __restrict__ dst,
                          int* __restrict__ bcur, unsigned* __restrict__ EB, int nE, int nB) {
    __shared__ int h[NBMAX], loff[NBMAX], gbase[NBMAX], lcur[NBMAX];
    __shared__ int ps[256];
    __shared__ uint2 stage[CH];
    int t = threadIdx.x;
    int e0 = blockIdx.x * CH;
    int ecnt = min(CH, nE - e0);
    if (ecnt <= 0) return;
    for (int i = t; i < nB; i += 256) h[i] = 0;
    __syncthreads();
    for (int i = t; i < ecnt; i += 256) atomicAdd(&h[dst[e0 + i] >> BSH], 1);
    __syncthreads();
    int b0 = 2 * t, b1 = 2 * t + 1;
    int c0 = (b0 < nB) ? h[b0] : 0;
    int c1 = (b1 < nB) ? h[b1] : 0;
    ps[t] = c0 + c1; __syncthreads();
    for (int off = 1; off < 256; off <<= 1) {
        int v = (t >= off) ? ps[t - off] : 0; __syncthreads();
        ps[t] += v; __syncthreads();
    }
    int excl = ps[t] - (c0 + c1);
    if (b0 < nB) { loff[b0] = excl;      lcur[b0] = excl; }
    if (b1 < nB) { loff[b1] = excl + c0; lcur[b1] = excl + c0; }
    __syncthreads();
    for (int i = t; i < nB; i += 256)
        if (h[i]) gbase[i] = atomicAdd(&bcur[i], h[i]);
    __syncthreads();
    for (int i = t; i < ecnt; i += 256) {
        int d = dst[e0 + i], s = src[e0 + i];
        int b = d >> BSH;
        int p = atomicAdd(&lcur[b], 1);
        stage[p] = make_uint2((unsigned)s, (unsigned)d);
    }
    __syncthreads();
    for (int i = t; i < ecnt; i += 256) {
        uint2 v = stage[i];
        int bb = (int)(v.y >> BSH);
        EB[gbase[bb] + (i - loff[bb])] = v.x | ((v.y & (BNODES - 1)) << SRCBITS);
    }
}

// ---------- per-bucket counting sort -> PADDED csr (x4, sentinel nN), dinv, rs ----------
__global__ void __launch_bounds__(256)
bucketSortK(const unsigned* __restrict__ EB, const int* __restrict__ boff,
            int* __restrict__ rowptr, int* __restrict__ rowend, int* __restrict__ csrP,
            float* __restrict__ dinv, float* __restrict__ rs, int nN, int nB) {
    __shared__ int hist[BNODES];
    __shared__ int cur[BNODES];
    __shared__ int ps[256];
    int b = blockIdx.x, t = threadIdx.x;
    int beg = boff[b], end = boff[b + 1];
    hist[t] = 0;
    __syncthreads();
    for (int i = beg + t; i < end; i += 256) atomicAdd(&hist[EB[i] >> SRCBITS], 1);
    __syncthreads();
    int deg = hist[t];
    int pdeg = (deg + 3) & ~3;
    ps[t] = pdeg; __syncthreads();
    for (int off = 1; off < 256; off <<= 1) {
        int v = (t >= off) ? ps[t - off] : 0; __syncthreads();
        ps[t] += v; __syncthreads();
    }
    int base = ((beg + 3) & ~3) + b * PADMAX;
    int excl = base + ps[t] - pdeg;
    int node = (b << BSH) + t;
    if (node < nN) {
        rowptr[node] = excl;
        rowend[node] = excl + pdeg;
        dinv[node] = rsqrtf((float)deg + 1.0f);
        rs[node] = sqrtf((float)deg + 1.0f);
    }
    cur[t] = excl;
    __syncthreads();
    for (int i = beg + t; i < end; i += 256) {
        unsigned v = EB[i];
        int p = atomicAdd(&cur[v >> SRCBITS], 1);
        csrP[p] = (int)(v & SRCMASK);
    }
    __syncthreads();
    // fill sentinel pads (<=3 per node)
    for (int p = cur[t]; p < excl + pdeg; ++p) csrP[p] = nN;
}

// ---------- g1 = bf16((x @ W1) * dinv), chunked [2][nN+1][16] ----------
__global__ void gemm1_kernel(const float4* __restrict__ x4, const float* __restrict__ W1,
                             const float* __restrict__ dinv, unsigned* __restrict__ Gc,
                             int nN) {
    __shared__ float Ws[FEAT_IN * F1];
    __shared__ float xs[8][FEAT_IN];
    for (int t = threadIdx.x; t < FEAT_IN * F1; t += 256) Ws[t] = W1[t];
    int rb = blockIdx.x * 8;
    {
        int r = threadIdx.x >> 5, c = threadIdx.x & 31;
        int row = rb + r;
        float4 v = (row < nN) ? x4[(size_t)row * 32 + c] : make_float4(0, 0, 0, 0);
        ((float4*)xs[r])[c] = v;
    }
    __syncthreads();
    int r = threadIdx.x >> 5;
    int row = rb + r;
    if (row >= nN) return;
    int j = threadIdx.x & 31;
    float acc = 0.f;
#pragma unroll 8
    for (int k = 0; k < FEAT_IN; ++k) acc = fmaf(xs[r][k], Ws[k * F1 + j], acc);
    float g = acc * dinv[row];
    float other = __shfl_xor(g, 1);
    if ((j & 1) == 0) {
        int c = j >> 4;                       // chunk
        int w = (j & 15) >> 1;                // u32 slot in row
        Gc[((size_t)c * (nN + 1) + row) * 8 + w] = f2bf(g) | (f2bf(other) << 16);
    }
}

// ---------- agg1: ILP-4 gather over chunk, write H chunk (bf16) ----------
__global__ void __launch_bounds__(256)
agg1v2(const int* __restrict__ rowptr, const int* __restrict__ rowend,
       const int* __restrict__ csrP, const unsigned* __restrict__ Gc,
       const float* __restrict__ dinv, const float* __restrict__ b1,
       unsigned* __restrict__ Hc, int nN, int K) {
    int b = blockIdx.x;
    int xcd = b & 7;
    int c = xcd & 1;
    int k = (b >> 3) * 4 + (xcd >> 1);
    if (k >= K) return;
    int t = threadIdx.x, wv = t >> 6, lane = t & 63;
    int node = k * 16 + wv * 4 + (lane >> 4);
    int slot = (lane >> 1) & 7, comp = lane & 1;
    bool vn = node < nN;
    const uint4* Gch = (const uint4*)(Gc + (size_t)c * (nN + 1) * 8);
    float a[8] = {0, 0, 0, 0, 0, 0, 0, 0};
    if (vn) {
        if ((lane & 14) == 0) bfacc8(a, Gch[(size_t)node * 2 + comp]);  // self-loop
        int beg = rowptr[node], endp = rowend[node];
        for (int e = beg + slot * 4; e < endp; e += 32) {
            int4 idx = *(const int4*)(csrP + e);
            uint4 r0 = Gch[(size_t)idx.x * 2 + comp];
            uint4 r1 = Gch[(size_t)idx.y * 2 + comp];
            uint4 r2 = Gch[(size_t)idx.z * 2 + comp];
            uint4 r3 = Gch[(size_t)idx.w * 2 + comp];
            bfacc8(a, r0); bfacc8(a, r1); bfacc8(a, r2); bfacc8(a, r3);
        }
    }
#pragma unroll
    for (int m = 2; m < 16; m <<= 1) {
#pragma unroll
        for (int i = 0; i < 8; ++i) a[i] += __shfl_xor(a[i], m);
    }
    if (vn && (lane & 14) == 0) {
        float dv = dinv[node];
        const float* bb = b1 + c * 16 + comp * 8;
        float h[8];
#pragma unroll
        for (int i = 0; i < 8; ++i) {
            float x1 = fmaxf(fmaf(dv, a[i], bb[i]), 0.f);
            h[i] = dv * x1;
        }
        uint4 hp;
        hp.x = f2bf(h[0]) | (f2bf(h[1]) << 16);
        hp.y = f2bf(h[2]) | (f2bf(h[3]) << 16);
        hp.z = f2bf(h[4]) | (f2bf(h[5]) << 16);
        hp.w = f2bf(h[6]) | (f2bf(h[7]) << 16);
        ((uint4*)(Hc + (size_t)c * (nN + 1) * 8))[(size_t)node * 2 + comp] = hp;
    }
}

// ---------- agg2: ILP-4 gather over H chunk, write A2 fp32 [nN][32] ----------
__global__ void __launch_bounds__(256)
agg2v2(const int* __restrict__ rowptr, const int* __restrict__ rowend,
       const int* __restrict__ csrP, const unsigned* __restrict__ Hc,
       const float* __restrict__ dinv, float* __restrict__ A2, int nN, int K) {
    int b = blockIdx.x;
    int xcd = b & 7;
    int c = xcd & 1;
    int k = (b >> 3) * 4 + (xcd >> 1);
    if (k >= K) return;
    int t = threadIdx.x, wv = t >> 6, lane = t & 63;
    int node = k * 16 + wv * 4 + (lane >> 4);
    int slot = (lane >> 1) & 7, comp = lane & 1;
    bool vn = node < nN;
    const uint4* Hch = (const uint4*)(Hc + (size_t)c * (nN + 1) * 8);
    float a[8] = {0, 0, 0, 0, 0, 0, 0, 0};
    if (vn) {
        if ((lane & 14) == 0) bfacc8(a, Hch[(size_t)node * 2 + comp]);  // self-loop
        int beg = rowptr[node], endp = rowend[node];
        for (int e = beg + slot * 4; e < endp; e += 32) {
            int4 idx = *(const int4*)(csrP + e);
            uint4 r0 = Hch[(size_t)idx.x * 2 + comp];
            uint4 r1 = Hch[(size_t)idx.y * 2 + comp];
            uint4 r2 = Hch[(size_t)idx.z * 2 + comp];
            uint4 r3 = Hch[(size_t)idx.w * 2 + comp];
            bfacc8(a, r0); bfacc8(a, r1); bfacc8(a, r2); bfacc8(a, r3);
        }
    }
#pragma unroll
    for (int m = 2; m < 16; m <<= 1) {
#pragma unroll
        for (int i = 0; i < 8; ++i) a[i] += __shfl_xor(a[i], m);
    }
    if (vn && (lane & 14) == 0) {
        float dv = dinv[node];
        float* dst = A2 + (size_t)node * F1 + c * 16 + comp * 8;
        float4 o0 = make_float4(dv * a[0], dv * a[1], dv * a[2], dv * a[3]);
        float4 o1 = make_float4(dv * a[4], dv * a[5], dv * a[6], dv * a[7]);
        ((float4*)dst)[0] = o0;
        ((float4*)dst)[1] = o1;
    }
}

// ---------- pool x1 from Hc: x1 = H * rs (dense-lane atomics) ----------
__global__ void poolH(const unsigned* __restrict__ Hc, const float* __restrict__ rs,
                      const int* __restrict__ batch, float* __restrict__ psum, int nN) {
    int gid = blockIdx.x * blockDim.x + threadIdx.x;
    int total = nN * 16;
    if (gid >= total) return;
    int n = gid >> 4, q = gid & 15;
    int c = q >> 3, w = q & 7;
    unsigned v = Hc[((size_t)c * (nN + 1) + n) * 8 + w];
    float r = rs[n];
    int feat = c * 16 + w * 2;
    int bg = batch[n];
    atomicAdd(&psum[(size_t)bg * FJ + feat + 0], bf2f(v & 0xffffu) * r);
    atomicAdd(&psum[(size_t)bg * FJ + feat + 1], bf2f(v >> 16) * r);
}

// ---------- x2 = relu(A2 @ W2 + b2), fused pool ----------
__global__ void gemm2pool(const float* __restrict__ A2, const float* __restrict__ W2,
                          const float* __restrict__ b2, const int* __restrict__ batch,
                          float* __restrict__ psum, int nN) {
    __shared__ float W2s[F1 * F2];
    __shared__ float aL[4][F1];
    for (int t = threadIdx.x; t < F1 * F2; t += 256) W2s[t] = W2[t];
    int wv = threadIdx.x >> 6, lane = threadIdx.x & 63;
    int node = blockIdx.x * 4 + wv;
    if (node < nN && lane < F1) aL[wv][lane] = A2[(size_t)node * F1 + lane];
    __syncthreads();
    if (node >= nN) return;
    float dot = 0.f;
#pragma unroll
    for (int kk = 0; kk < F1; ++kk) dot = fmaf(aL[wv][kk], W2s[kk * F2 + lane], dot);
    float x2 = fmaxf(dot + b2[lane], 0.f);
    atomicAdd(&psum[(size_t)batch[node] * FJ + F1 + lane], x2);
}

__global__ void cnt_kernel(const int* __restrict__ batch, float* __restrict__ cnt, int nN) {
    int i = blockIdx.x * blockDim.x + threadIdx.x;
    if (i < nN) atomicAdd(&cnt[batch[i]], 1.0f);
}

__global__ void mlp_kernel(const float* __restrict__ psum, const float* __restrict__ cnt,
                           const float* __restrict__ fW1, const float* __restrict__ fb1,
                           const float* __restrict__ fW2, const float* __restrict__ fb2,
                           float* __restrict__ out) {
    __shared__ float p[FJ];
    __shared__ float red[FH];
    int g = blockIdx.x, tid = threadIdx.x;
    float c = fmaxf(cnt[g], 1.0f);
    if (tid < FJ) p[tid] = psum[g * FJ + tid] / c;
    __syncthreads();
    float acc = fb1[tid];
    for (int k = 0; k < FJ; ++k) acc = fmaf(p[k], fW1[k * FH + tid], acc);
    float h = fmaxf(acc, 0.f);
    red[tid] = h * fW2[tid];
    __syncthreads();
    for (int s = FH / 2; s > 0; s >>= 1) {
        if (tid < s) red[tid] += red[tid + s];
        __syncthreads();
    }
    if (tid == 0) out[g] = red[0] + fb2[0];
}

extern "C" void kernel_launch(void* const* d_in, const int* in_sizes, int n_in,
                              void* d_out, int out_size, void* d_ws, size_t ws_size,
                              hipStream_t stream) {
    const float* x   = (const float*)d_in[0];
    const int*   ei  = (const int*)d_in[1];
    const int*   bat = (const int*)d_in[2];
    const float* W1  = (const float*)d_in[3];
    const float* b1  = (const float*)d_in[4];
    const float* W2  = (const float*)d_in[5];
    const float* b2  = (const float*)d_in[6];
    const float* fW1 = (const float*)d_in[7];
    const float* fb1 = (const float*)d_in[8];
    const float* fW2 = (const float*)d_in[9];
    const float* fb2 = (const float*)d_in[10];
    float* out = (float*)d_out;

    int nN = in_sizes[0] / FEAT_IN;
    int nE = in_sizes[1] / 2;
    int nG = out_size;
    const int* src = ei;
    const int* dst = ei + nE;

    int nB  = (nN + BNODES - 1) >> BSH;
    int nCh = (nE + CH - 1) / CH;
    int K   = (nN + 15) / 16;            // 16 nodes per block (4 waves x 4 nodes)
    int gridC = ((K + 3) / 4) * 8;       // XCD-pinned: 8 blocks cover {2 chunks x 4 k}

    char* w = (char*)d_ws;
    auto alloc = [&](size_t bytes) { char* p = w; w += (bytes + 15) & ~(size_t)15; return p; };
    int*      bcnt   = (int*)alloc(NBMAX * 4);
    int*      boff   = (int*)alloc((NBMAX + 1) * 4);
    int*      bcur   = (int*)alloc(NBMAX * 4);
    unsigned* EB     = (unsigned*)alloc((size_t)nE * 4);
    int*      rowptr = (int*)alloc((size_t)nN * 4);
    int*      rowend = (int*)alloc((size_t)nN * 4);
    int*      csrP   = (int*)alloc(((size_t)nE + (size_t)NBMAX * PADMAX + 64) * 4);
    float*    dinv   = (float*)alloc((size_t)nN * 4);
    float*    rsb    = (float*)alloc((size_t)nN * 4);
    unsigned* Gc     = (unsigned*)alloc((size_t)2 * (nN + 1) * 16 * 2);  // bf16 [2][nN+1][16]
    unsigned* Hc     = (unsigned*)alloc((size_t)2 * (nN + 1) * 16 * 2);
    float*    A2     = (float*)alloc((size_t)nN * F1 * 4);
    float*    psum   = (float*)alloc((size_t)nG * FJ * 4);
    float*    cnt    = (float*)alloc((size_t)nG * 4);

    hipMemsetAsync(bcnt, 0, NBMAX * 4, stream);
    hipMemsetAsync(psum, 0, (size_t)nG * FJ * 4, stream);
    hipMemsetAsync(cnt, 0, (size_t)nG * 4, stream);
    // zero sentinel rows (node nN) of each chunk in Gc and Hc
    for (int c = 0; c < 2; ++c) {
        hipMemsetAsync(Gc + ((size_t)c * (nN + 1) + nN) * 16, 0, 32, stream);
        hipMemsetAsync(Hc + ((size_t)c * (nN + 1) + nN) * 16, 0, 32, stream);
    }

    // CSR build (padded) via dst-buckets
    histA<<<1024, 256, 0, stream>>>(dst, bcnt, nE, nB);
    scanBk<<<1, 256, 0, stream>>>(bcnt, boff, bcur, nB, nE);
    scatterEB<<<nCh, 256, 0, stream>>>(src, dst, bcur, EB, nE, nB);
    bucketSortK<<<nB, 256, 0, stream>>>(EB, boff, rowptr, rowend, csrP, dinv, rsb, nN, nB);

    // layer 1
    gemm1_kernel<<<(nN + 7) / 8, 256, 0, stream>>>((const float4*)x, W1, dinv, Gc, nN);
    agg1v2<<<gridC, 256, 0, stream>>>(rowptr, rowend, csrP, Gc, dinv, b1, Hc, nN, K);
    // layer 2
    agg2v2<<<gridC, 256, 0, stream>>>(rowptr, rowend, csrP, Hc, dinv, A2, nN, K);
    gemm2pool<<<(nN + 3) / 4, 256, 0, stream>>>(A2, W2, b2, bat, psum, nN);

    // pooling of x1 (reconstructed from Hc) + counts + MLP
    poolH<<<(nN * 16 + 255) / 256, 256, 0, stream>>>(Hc, rsb, bat, psum, nN);
    cnt_kernel<<<(nN + 255) / 256, 256, 0, stream>>>(bat, cnt, nN);
    mlp_kernel<<<nG, FH, 0, stream>>>(psum, cnt, fW1, fb1, fW2, fb2, out);
}

// Round 10
// 453.908 us; speedup vs baseline: 1.4607x; 1.1203x over previous
//
#include <hip/hip_runtime.h>
#include <stdint.h>

#define FEAT_IN 128
#define F1 32
#define F2 64
#define FJ 96
#define FH 128

#define BSH 8                  // 256 nodes per bucket
#define BNODES 256
#define NBMAX 512
#define CH 8192
#define SRCBITS 17             // nN must be < 2^17
#define SRCMASK 0x1FFFFu
#define PADMAX 768             // max pad per bucket (256 nodes * 3)
#define PNPB 1024              // nodes per block in poolX1

__device__ __forceinline__ unsigned f2bf(float f) {
    unsigned u = __float_as_uint(f);
    return (u + 0x7FFFu + ((u >> 16) & 1u)) >> 16;   // RNE
}
__device__ __forceinline__ float bf2f(unsigned h) { return __uint_as_float(h << 16); }
__device__ __forceinline__ void bfacc8(float* a, uint4 v) {
    a[0] += bf2f(v.x & 0xffffu); a[1] += bf2f(v.x >> 16);
    a[2] += bf2f(v.y & 0xffffu); a[3] += bf2f(v.y >> 16);
    a[4] += bf2f(v.z & 0xffffu); a[5] += bf2f(v.z >> 16);
    a[6] += bf2f(v.w & 0xffffu); a[7] += bf2f(v.w >> 16);
}

// ---------- bucket histogram ----------
__global__ void histA(const int* __restrict__ dst, int* __restrict__ bcnt, int nE, int nB) {
    __shared__ int h[NBMAX];
    for (int t = threadIdx.x; t < nB; t += blockDim.x) h[t] = 0;
    __syncthreads();
    int stride = gridDim.x * blockDim.x;
    for (int e = blockIdx.x * blockDim.x + threadIdx.x; e < nE; e += stride)
        atomicAdd(&h[dst[e] >> BSH], 1);
    __syncthreads();
    for (int t = threadIdx.x; t < nB; t += blockDim.x)
        if (h[t]) atomicAdd(&bcnt[t], h[t]);
}

// ---------- scan buckets ----------
__global__ void scanBk(const int* __restrict__ bcnt, int* __restrict__ boff,
                       int* __restrict__ bcur, int nB, int nE) {
    __shared__ int ps[256];
    int t = threadIdx.x;
    int c[4]; int s = 0;
#pragma unroll
    for (int k = 0; k < 4; ++k) { int b = t * 4 + k; c[k] = (b < nB) ? bcnt[b] : 0; s += c[k]; }
    ps[t] = s; __syncthreads();
    for (int off = 1; off < 256; off <<= 1) {
        int v = (t >= off) ? ps[t - off] : 0; __syncthreads();
        ps[t] += v; __syncthreads();
    }
    int excl = ps[t] - s;
#pragma unroll
    for (int k = 0; k < 4; ++k) {
        int b = t * 4 + k;
        if (b < nB) { boff[b] = excl; bcur[b] = excl; excl += c[k]; }
    }
    if (t == 255) boff[nB] = nE;
}

// ---------- scatter edges into buckets, LDS-staged ----------
__global__ void scatterEB(const int* __restrict__ src, const int* __restrict__ dst,
                          int* __restrict__ bcur, unsigned* __restrict__ EB, int nE, int nB) {
    __shared__ int h[NBMAX], loff[NBMAX], gbase[NBMAX], lcur[NBMAX];
    __shared__ int ps[256];
    __shared__ uint2 stage[CH];
    int t = threadIdx.x;
    int e0 = blockIdx.x * CH;
    int ecnt = min(CH, nE - e0);
    if (ecnt <= 0) return;
    for (int i = t; i < nB; i += 256) h[i] = 0;
    __syncthreads();
    for (int i = t; i < ecnt; i += 256) atomicAdd(&h[dst[e0 + i] >> BSH], 1);
    __syncthreads();
    int b0 = 2 * t, b1 = 2 * t + 1;
    int c0 = (b0 < nB) ? h[b0] : 0;
    int c1 = (b1 < nB) ? h[b1] : 0;
    ps[t] = c0 + c1; __syncthreads();
    for (int off = 1; off < 256; off <<= 1) {
        int v = (t >= off) ? ps[t - off] : 0; __syncthreads();
        ps[t] += v; __syncthreads();
    }
    int excl = ps[t] - (c0 + c1);
    if (b0 < nB) { loff[b0] = excl;      lcur[b0] = excl; }
    if (b1 < nB) { loff[b1] = excl + c0; lcur[b1] = excl + c0; }
    __syncthreads();
    for (int i = t; i < nB; i += 256)
        if (h[i]) gbase[i] = atomicAdd(&bcur[i], h[i]);
    __syncthreads();
    for (int i = t; i < ecnt; i += 256) {
        int d = dst[e0 + i], s = src[e0 + i];
        int b = d >> BSH;
        int p = atomicAdd(&lcur[b], 1);
        stage[p] = make_uint2((unsigned)s, (unsigned)d);
    }
    __syncthreads();
    for (int i = t; i < ecnt; i += 256) {
        uint2 v = stage[i];
        int bb = (int)(v.y >> BSH);
        EB[gbase[bb] + (i - loff[bb])] = v.x | ((v.y & (BNODES - 1)) << SRCBITS);
    }
}

// ---------- per-bucket counting sort -> PADDED csr (x4, sentinel nN), dinv, rs ----------
__global__ void __launch_bounds__(256)
bucketSortK(const unsigned* __restrict__ EB, const int* __restrict__ boff,
            int* __restrict__ rowptr, int* __restrict__ rowend, int* __restrict__ csrP,
            float* __restrict__ dinv, float* __restrict__ rs, int nN, int nB) {
    __shared__ int hist[BNODES];
    __shared__ int cur[BNODES];
    __shared__ int ps[256];
    int b = blockIdx.x, t = threadIdx.x;
    int beg = boff[b], end = boff[b + 1];
    hist[t] = 0;
    __syncthreads();
    for (int i = beg + t; i < end; i += 256) atomicAdd(&hist[EB[i] >> SRCBITS], 1);
    __syncthreads();
    int deg = hist[t];
    int pdeg = (deg + 3) & ~3;
    ps[t] = pdeg; __syncthreads();
    for (int off = 1; off < 256; off <<= 1) {
        int v = (t >= off) ? ps[t - off] : 0; __syncthreads();
        ps[t] += v; __syncthreads();
    }
    int base = ((beg + 3) & ~3) + b * PADMAX;
    int excl = base + ps[t] - pdeg;
    int node = (b << BSH) + t;
    if (node < nN) {
        rowptr[node] = excl;
        rowend[node] = excl + pdeg;
        dinv[node] = rsqrtf((float)deg + 1.0f);
        rs[node] = sqrtf((float)deg + 1.0f);
    }
    cur[t] = excl;
    __syncthreads();
    for (int i = beg + t; i < end; i += 256) {
        unsigned v = EB[i];
        int p = atomicAdd(&cur[v >> SRCBITS], 1);
        csrP[p] = (int)(v & SRCMASK);
    }
    __syncthreads();
    // fill sentinel pads (<=3 per node)
    for (int p = cur[t]; p < excl + pdeg; ++p) csrP[p] = nN;
}

// ---------- g1 = bf16((x @ W1) * dinv), chunked [2][nN+1][16] ----------
__global__ void gemm1_kernel(const float4* __restrict__ x4, const float* __restrict__ W1,
                             const float* __restrict__ dinv, unsigned* __restrict__ Gc,
                             int nN) {
    __shared__ float Ws[FEAT_IN * F1];
    __shared__ float xs[8][FEAT_IN];
    for (int t = threadIdx.x; t < FEAT_IN * F1; t += 256) Ws[t] = W1[t];
    int rb = blockIdx.x * 8;
    {
        int r = threadIdx.x >> 5, c = threadIdx.x & 31;
        int row = rb + r;
        float4 v = (row < nN) ? x4[(size_t)row * 32 + c] : make_float4(0, 0, 0, 0);
        ((float4*)xs[r])[c] = v;
    }
    __syncthreads();
    int r = threadIdx.x >> 5;
    int row = rb + r;
    if (row >= nN) return;
    int j = threadIdx.x & 31;
    float acc = 0.f;
#pragma unroll 8
    for (int k = 0; k < FEAT_IN; ++k) acc = fmaf(xs[r][k], Ws[k * F1 + j], acc);
    float g = acc * dinv[row];
    float other = __shfl_xor(g, 1);
    if ((j & 1) == 0) {
        int c = j >> 4;                       // chunk
        int w = (j & 15) >> 1;                // u32 slot in row
        Gc[((size_t)c * (nN + 1) + row) * 8 + w] = f2bf(g) | (f2bf(other) << 16);
    }
}

// ---------- agg1: ILP-4 gather over chunk, write H chunk (bf16) ----------
__global__ void __launch_bounds__(256)
agg1v2(const int* __restrict__ rowptr, const int* __restrict__ rowend,
       const int* __restrict__ csrP, const unsigned* __restrict__ Gc,
       const float* __restrict__ dinv, const float* __restrict__ b1,
       unsigned* __restrict__ Hc, int nN, int K) {
    int b = blockIdx.x;
    int xcd = b & 7;
    int c = xcd & 1;
    int k = (b >> 3) * 4 + (xcd >> 1);
    if (k >= K) return;
    int t = threadIdx.x, wv = t >> 6, lane = t & 63;
    int node = k * 16 + wv * 4 + (lane >> 4);
    int slot = (lane >> 1) & 7, comp = lane & 1;
    bool vn = node < nN;
    const uint4* Gch = (const uint4*)(Gc + (size_t)c * (nN + 1) * 8);
    float a[8] = {0, 0, 0, 0, 0, 0, 0, 0};
    if (vn) {
        if ((lane & 14) == 0) bfacc8(a, Gch[(size_t)node * 2 + comp]);  // self-loop
        int beg = rowptr[node], endp = rowend[node];
        for (int e = beg + slot * 4; e < endp; e += 32) {
            int4 idx = *(const int4*)(csrP + e);
            uint4 r0 = Gch[(size_t)idx.x * 2 + comp];
            uint4 r1 = Gch[(size_t)idx.y * 2 + comp];
            uint4 r2 = Gch[(size_t)idx.z * 2 + comp];
            uint4 r3 = Gch[(size_t)idx.w * 2 + comp];
            bfacc8(a, r0); bfacc8(a, r1); bfacc8(a, r2); bfacc8(a, r3);
        }
    }
#pragma unroll
    for (int m = 2; m < 16; m <<= 1) {
#pragma unroll
        for (int i = 0; i < 8; ++i) a[i] += __shfl_xor(a[i], m);
    }
    if (vn && (lane & 14) == 0) {
        float dv = dinv[node];
        const float* bb = b1 + c * 16 + comp * 8;
        float h[8];
#pragma unroll
        for (int i = 0; i < 8; ++i) {
            float x1 = fmaxf(fmaf(dv, a[i], bb[i]), 0.f);
            h[i] = dv * x1;
        }
        uint4 hp;
        hp.x = f2bf(h[0]) | (f2bf(h[1]) << 16);
        hp.y = f2bf(h[2]) | (f2bf(h[3]) << 16);
        hp.z = f2bf(h[4]) | (f2bf(h[5]) << 16);
        hp.w = f2bf(h[6]) | (f2bf(h[7]) << 16);
        ((uint4*)(Hc + (size_t)c * (nN + 1) * 8))[(size_t)node * 2 + comp] = hp;
    }
}

// ---------- agg2: ILP-4 gather over H chunk, write A2 fp32 [nN][32] ----------
__global__ void __launch_bounds__(256)
agg2v2(const int* __restrict__ rowptr, const int* __restrict__ rowend,
       const int* __restrict__ csrP, const unsigned* __restrict__ Hc,
       const float* __restrict__ dinv, float* __restrict__ A2, int nN, int K) {
    int b = blockIdx.x;
    int xcd = b & 7;
    int c = xcd & 1;
    int k = (b >> 3) * 4 + (xcd >> 1);
    if (k >= K) return;
    int t = threadIdx.x, wv = t >> 6, lane = t & 63;
    int node = k * 16 + wv * 4 + (lane >> 4);
    int slot = (lane >> 1) & 7, comp = lane & 1;
    bool vn = node < nN;
    const uint4* Hch = (const uint4*)(Hc + (size_t)c * (nN + 1) * 8);
    float a[8] = {0, 0, 0, 0, 0, 0, 0, 0};
    if (vn) {
        if ((lane & 14) == 0) bfacc8(a, Hch[(size_t)node * 2 + comp]);  // self-loop
        int beg = rowptr[node], endp = rowend[node];
        for (int e = beg + slot * 4; e < endp; e += 32) {
            int4 idx = *(const int4*)(csrP + e);
            uint4 r0 = Hch[(size_t)idx.x * 2 + comp];
            uint4 r1 = Hch[(size_t)idx.y * 2 + comp];
            uint4 r2 = Hch[(size_t)idx.z * 2 + comp];
            uint4 r3 = Hch[(size_t)idx.w * 2 + comp];
            bfacc8(a, r0); bfacc8(a, r1); bfacc8(a, r2); bfacc8(a, r3);
        }
    }
#pragma unroll
    for (int m = 2; m < 16; m <<= 1) {
#pragma unroll
        for (int i = 0; i < 8; ++i) a[i] += __shfl_xor(a[i], m);
    }
    if (vn && (lane & 14) == 0) {
        float dv = dinv[node];
        float* dst = A2 + (size_t)node * F1 + c * 16 + comp * 8;
        float4 o0 = make_float4(dv * a[0], dv * a[1], dv * a[2], dv * a[3]);
        float4 o1 = make_float4(dv * a[4], dv * a[5], dv * a[6], dv * a[7]);
        ((float4*)dst)[0] = o0;
        ((float4*)dst)[1] = o1;
    }
}

// ---------- segmented pool of x1 from Hc (batch sorted; flush on graph change) ----------
__global__ void __launch_bounds__(256)
poolX1(const unsigned* __restrict__ Hc, const float* __restrict__ rs,
       const int* __restrict__ batch, float* __restrict__ psum, int nN) {
    int t = threadIdx.x, wv = t >> 6, lane = t & 63;
    int c = wv >> 1, half = wv & 1;
    int base = blockIdx.x * PNPB + half * (PNPB / 2);
    int w32 = lane & 7, noff = lane >> 3;
    const unsigned* Hch = Hc + (size_t)c * (nN + 1) * 8;
    int feat = c * 16 + w32 * 2;
    float a0 = 0.f, a1 = 0.f;
    int curG = -1;
#pragma unroll 4
    for (int i = 0; i < PNPB / 16; ++i) {
        int node = base + noff + 8 * i;
        if (node >= nN) break;
        int bg = batch[node];
        if (bg != curG) {
            if (curG >= 0) {
                atomicAdd(&psum[(size_t)curG * FJ + feat + 0], a0);
                atomicAdd(&psum[(size_t)curG * FJ + feat + 1], a1);
            }
            a0 = a1 = 0.f; curG = bg;
        }
        unsigned v = Hch[(size_t)node * 8 + w32];
        float r = rs[node];
        a0 = fmaf(bf2f(v & 0xffffu), r, a0);
        a1 = fmaf(bf2f(v >> 16), r, a1);
    }
    if (curG >= 0) {
        atomicAdd(&psum[(size_t)curG * FJ + feat + 0], a0);
        atomicAdd(&psum[(size_t)curG * FJ + feat + 1], a1);
    }
}

// ---------- segmented x2 pool: per-node W2 transform + relu, flush on graph change ----------
__global__ void __launch_bounds__(256)
poolX2(const float* __restrict__ A2, const float* __restrict__ W2,
       const float* __restrict__ b2, const int* __restrict__ batch,
       float* __restrict__ psum, int nN) {
    __shared__ float W2s[F1 * F2];
    for (int i = threadIdx.x; i < F1 * F2; i += 256) W2s[i] = W2[i];
    __syncthreads();
    int wv = threadIdx.x >> 6, lane = threadIdx.x & 63;
    int nbase = blockIdx.x * 256 + wv * 64;
    float bj = b2[lane];
    float acc = 0.f;
    int curG = -1;
    for (int i = 0; i < 64; ++i) {
        int node = nbase + i;
        if (node >= nN) break;
        int bg = batch[node];
        if (bg != curG) {
            if (curG >= 0) atomicAdd(&psum[(size_t)curG * FJ + F1 + lane], acc);
            acc = 0.f; curG = bg;
        }
        float av = (lane < F1) ? A2[(size_t)node * F1 + lane] : 0.f;
        float dot = 0.f;
#pragma unroll
        for (int k = 0; k < F1; ++k) dot = fmaf(__shfl(av, k), W2s[k * F2 + lane], dot);
        acc += fmaxf(dot + bj, 0.f);
    }
    if (curG >= 0) atomicAdd(&psum[(size_t)curG * FJ + F1 + lane], acc);
}

__global__ void cnt_kernel(const int* __restrict__ batch, float* __restrict__ cnt, int nN) {
    int i = blockIdx.x * blockDim.x + threadIdx.x;
    if (i < nN) atomicAdd(&cnt[batch[i]], 1.0f);
}

__global__ void mlp_kernel(const float* __restrict__ psum, const float* __restrict__ cnt,
                           const float* __restrict__ fW1, const float* __restrict__ fb1,
                           const float* __restrict__ fW2, const float* __restrict__ fb2,
                           float* __restrict__ out) {
    __shared__ float p[FJ];
    __shared__ float red[FH];
    int g = blockIdx.x, tid = threadIdx.x;
    float c = fmaxf(cnt[g], 1.0f);
    if (tid < FJ) p[tid] = psum[g * FJ + tid] / c;
    __syncthreads();
    float acc = fb1[tid];
    for (int k = 0; k < FJ; ++k) acc = fmaf(p[k], fW1[k * FH + tid], acc);
    float h = fmaxf(acc, 0.f);
    red[tid] = h * fW2[tid];
    __syncthreads();
    for (int s = FH / 2; s > 0; s >>= 1) {
        if (tid < s) red[tid] += red[tid + s];
        __syncthreads();
    }
    if (tid == 0) out[g] = red[0] + fb2[0];
}

extern "C" void kernel_launch(void* const* d_in, const int* in_sizes, int n_in,
                              void* d_out, int out_size, void* d_ws, size_t ws_size,
                              hipStream_t stream) {
    const float* x   = (const float*)d_in[0];
    const int*   ei  = (const int*)d_in[1];
    const int*   bat = (const int*)d_in[2];
    const float* W1  = (const float*)d_in[3];
    const float* b1  = (const float*)d_in[4];
    const float* W2  = (const float*)d_in[5];
    const float* b2  = (const float*)d_in[6];
    const float* fW1 = (const float*)d_in[7];
    const float* fb1 = (const float*)d_in[8];
    const float* fW2 = (const float*)d_in[9];
    const float* fb2 = (const float*)d_in[10];
    float* out = (float*)d_out;

    int nN = in_sizes[0] / FEAT_IN;
    int nE = in_sizes[1] / 2;
    int nG = out_size;
    const int* src = ei;
    const int* dst = ei + nE;

    int nB  = (nN + BNODES - 1) >> BSH;
    int nCh = (nE + CH - 1) / CH;
    int K   = (nN + 15) / 16;            // 16 nodes per block (4 waves x 4 nodes)
    int gridC = ((K + 3) / 4) * 8;       // XCD-pinned: 8 blocks cover {2 chunks x 4 k}

    char* w = (char*)d_ws;
    auto alloc = [&](size_t bytes) { char* p = w; w += (bytes + 15) & ~(size_t)15; return p; };
    int*      bcnt   = (int*)alloc(NBMAX * 4);
    int*      boff   = (int*)alloc((NBMAX + 1) * 4);
    int*      bcur   = (int*)alloc(NBMAX * 4);
    unsigned* EB     = (unsigned*)alloc((size_t)nE * 4);
    int*      rowptr = (int*)alloc((size_t)nN * 4);
    int*      rowend = (int*)alloc((size_t)nN * 4);
    int*      csrP   = (int*)alloc(((size_t)nE + (size_t)NBMAX * PADMAX + 64) * 4);
    float*    dinv   = (float*)alloc((size_t)nN * 4);
    float*    rsb    = (float*)alloc((size_t)nN * 4);
    unsigned* Gc     = (unsigned*)alloc((size_t)2 * (nN + 1) * 16 * 2);  // bf16 [2][nN+1][16]
    unsigned* Hc     = (unsigned*)alloc((size_t)2 * (nN + 1) * 16 * 2);
    float*    A2     = (float*)alloc((size_t)nN * F1 * 4);
    float*    psum   = (float*)alloc((size_t)nG * FJ * 4);
    float*    cnt    = (float*)alloc((size_t)nG * 4);

    hipMemsetAsync(bcnt, 0, NBMAX * 4, stream);
    hipMemsetAsync(psum, 0, (size_t)nG * FJ * 4, stream);
    hipMemsetAsync(cnt, 0, (size_t)nG * 4, stream);
    // zero sentinel rows (node nN) of each chunk in Gc and Hc
    for (int c = 0; c < 2; ++c) {
        hipMemsetAsync(Gc + ((size_t)c * (nN + 1) + nN) * 16, 0, 32, stream);
        hipMemsetAsync(Hc + ((size_t)c * (nN + 1) + nN) * 16, 0, 32, stream);
    }

    // CSR build (padded) via dst-buckets
    histA<<<1024, 256, 0, stream>>>(dst, bcnt, nE, nB);
    scanBk<<<1, 256, 0, stream>>>(bcnt, boff, bcur, nB, nE);
    scatterEB<<<nCh, 256, 0, stream>>>(src, dst, bcur, EB, nE, nB);
    bucketSortK<<<nB, 256, 0, stream>>>(EB, boff, rowptr, rowend, csrP, dinv, rsb, nN, nB);

    // layer 1
    gemm1_kernel<<<(nN + 7) / 8, 256, 0, stream>>>((const float4*)x, W1, dinv, Gc, nN);
    agg1v2<<<gridC, 256, 0, stream>>>(rowptr, rowend, csrP, Gc, dinv, b1, Hc, nN, K);
    // layer 2
    agg2v2<<<gridC, 256, 0, stream>>>(rowptr, rowend, csrP, Hc, dinv, A2, nN, K);

    // segmented pooling + counts + MLP
    poolX1<<<(nN + PNPB - 1) / PNPB, 256, 0, stream>>>(Hc, rsb, bat, psum, nN);
    poolX2<<<(nN + 255) / 256, 256, 0, stream>>>(A2, W2, b2, bat, psum, nN);
    cnt_kernel<<<(nN + 255) / 256, 256, 0, stream>>>(bat, cnt, nN);
    mlp_kernel<<<nG, FH, 0, stream>>>(psum, cnt, fW1, fb1, fW2, fb2, out);
}

// Round 11
// 357.993 us; speedup vs baseline: 1.8521x; 1.2679x over previous
//
#include <hip/hip_runtime.h>
#include <stdint.h>

#define FEAT_IN 128
#define F1 32
#define F2 64
#define FJ 96
#define FH 128

#define BSH 8                  // 256 nodes per bucket
#define BNODES 256
#define NBMAX 512
#define CH 8192
#define SRCBITS 17             // nN must be < 2^17
#define SRCMASK 0x1FFFFu
#define PADMAX 768             // max pad per bucket (256 nodes * 3)
#define PNPB 1024              // nodes per block in poolX1

__device__ __forceinline__ unsigned f2bf(float f) {
    unsigned u = __float_as_uint(f);
    return (u + 0x7FFFu + ((u >> 16) & 1u)) >> 16;   // RNE
}
__device__ __forceinline__ float bf2f(unsigned h) { return __uint_as_float(h << 16); }
__device__ __forceinline__ void bfacc8(float* a, uint4 v) {
    a[0] += bf2f(v.x & 0xffffu); a[1] += bf2f(v.x >> 16);
    a[2] += bf2f(v.y & 0xffffu); a[3] += bf2f(v.y >> 16);
    a[4] += bf2f(v.z & 0xffffu); a[5] += bf2f(v.z >> 16);
    a[6] += bf2f(v.w & 0xffffu); a[7] += bf2f(v.w >> 16);
}

// ---------- bucket histogram ----------
__global__ void histA(const int* __restrict__ dst, int* __restrict__ bcnt, int nE, int nB) {
    __shared__ int h[NBMAX];
    for (int t = threadIdx.x; t < nB; t += blockDim.x) h[t] = 0;
    __syncthreads();
    int stride = gridDim.x * blockDim.x;
    for (int e = blockIdx.x * blockDim.x + threadIdx.x; e < nE; e += stride)
        atomicAdd(&h[dst[e] >> BSH], 1);
    __syncthreads();
    for (int t = threadIdx.x; t < nB; t += blockDim.x)
        if (h[t]) atomicAdd(&bcnt[t], h[t]);
}

// ---------- scan buckets ----------
__global__ void scanBk(const int* __restrict__ bcnt, int* __restrict__ boff,
                       int* __restrict__ bcur, int nB, int nE) {
    __shared__ int ps[256];
    int t = threadIdx.x;
    int c[4]; int s = 0;
#pragma unroll
    for (int k = 0; k < 4; ++k) { int b = t * 4 + k; c[k] = (b < nB) ? bcnt[b] : 0; s += c[k]; }
    ps[t] = s; __syncthreads();
    for (int off = 1; off < 256; off <<= 1) {
        int v = (t >= off) ? ps[t - off] : 0; __syncthreads();
        ps[t] += v; __syncthreads();
    }
    int excl = ps[t] - s;
#pragma unroll
    for (int k = 0; k < 4; ++k) {
        int b = t * 4 + k;
        if (b < nB) { boff[b] = excl; bcur[b] = excl; excl += c[k]; }
    }
    if (t == 255) boff[nB] = nE;
}

// ---------- scatter edges into buckets, LDS-staged ----------
__global__ void scatterEB(const int* __restrict__ src, const int* __restrict__ dst,
                          int* __restrict__ bcur, unsigned* __restrict__ EB, int nE, int nB) {
    __shared__ int h[NBMAX], loff[NBMAX], gbase[NBMAX], lcur[NBMAX];
    __shared__ int ps[256];
    __shared__ uint2 stage[CH];
    int t = threadIdx.x;
    int e0 = blockIdx.x * CH;
    int ecnt = min(CH, nE - e0);
    if (ecnt <= 0) return;
    for (int i = t; i < nB; i += 256) h[i] = 0;
    __syncthreads();
    for (int i = t; i < ecnt; i += 256) atomicAdd(&h[dst[e0 + i] >> BSH], 1);
    __syncthreads();
    int b0 = 2 * t, b1 = 2 * t + 1;
    int c0 = (b0 < nB) ? h[b0] : 0;
    int c1 = (b1 < nB) ? h[b1] : 0;
    ps[t] = c0 + c1; __syncthreads();
    for (int off = 1; off < 256; off <<= 1) {
        int v = (t >= off) ? ps[t - off] : 0; __syncthreads();
        ps[t] += v; __syncthreads();
    }
    int excl = ps[t] - (c0 + c1);
    if (b0 < nB) { loff[b0] = excl;      lcur[b0] = excl; }
    if (b1 < nB) { loff[b1] = excl + c0; lcur[b1] = excl + c0; }
    __syncthreads();
    for (int i = t; i < nB; i += 256)
        if (h[i]) gbase[i] = atomicAdd(&bcur[i], h[i]);
    __syncthreads();
    for (int i = t; i < ecnt; i += 256) {
        int d = dst[e0 + i], s = src[e0 + i];
        int b = d >> BSH;
        int p = atomicAdd(&lcur[b], 1);
        stage[p] = make_uint2((unsigned)s, (unsigned)d);
    }
    __syncthreads();
    for (int i = t; i < ecnt; i += 256) {
        uint2 v = stage[i];
        int bb = (int)(v.y >> BSH);
        EB[gbase[bb] + (i - loff[bb])] = v.x | ((v.y & (BNODES - 1)) << SRCBITS);
    }
}

// ---------- per-bucket counting sort -> PADDED csr (x4, sentinel nN), dinv, rs ----------
__global__ void __launch_bounds__(256)
bucketSortK(const unsigned* __restrict__ EB, const int* __restrict__ boff,
            int* __restrict__ rowptr, int* __restrict__ rowend, int* __restrict__ csrP,
            float* __restrict__ dinv, float* __restrict__ rs, int nN, int nB) {
    __shared__ int hist[BNODES];
    __shared__ int cur[BNODES];
    __shared__ int ps[256];
    int b = blockIdx.x, t = threadIdx.x;
    int beg = boff[b], end = boff[b + 1];
    hist[t] = 0;
    __syncthreads();
    for (int i = beg + t; i < end; i += 256) atomicAdd(&hist[EB[i] >> SRCBITS], 1);
    __syncthreads();
    int deg = hist[t];
    int pdeg = (deg + 3) & ~3;
    ps[t] = pdeg; __syncthreads();
    for (int off = 1; off < 256; off <<= 1) {
        int v = (t >= off) ? ps[t - off] : 0; __syncthreads();
        ps[t] += v; __syncthreads();
    }
    int base = ((beg + 3) & ~3) + b * PADMAX;
    int excl = base + ps[t] - pdeg;
    int node = (b << BSH) + t;
    if (node < nN) {
        rowptr[node] = excl;
        rowend[node] = excl + pdeg;
        dinv[node] = rsqrtf((float)deg + 1.0f);
        rs[node] = sqrtf((float)deg + 1.0f);
    }
    cur[t] = excl;
    __syncthreads();
    for (int i = beg + t; i < end; i += 256) {
        unsigned v = EB[i];
        int p = atomicAdd(&cur[v >> SRCBITS], 1);
        csrP[p] = (int)(v & SRCMASK);
    }
    __syncthreads();
    // fill sentinel pads (<=3 per node)
    for (int p = cur[t]; p < excl + pdeg; ++p) csrP[p] = nN;
}

// ---------- g1 = bf16((x @ W1) * dinv), chunked [2][nN+1][16] ----------
__global__ void gemm1_kernel(const float4* __restrict__ x4, const float* __restrict__ W1,
                             const float* __restrict__ dinv, unsigned* __restrict__ Gc,
                             int nN) {
    __shared__ float Ws[FEAT_IN * F1];
    __shared__ float xs[8][FEAT_IN];
    for (int t = threadIdx.x; t < FEAT_IN * F1; t += 256) Ws[t] = W1[t];
    int rb = blockIdx.x * 8;
    {
        int r = threadIdx.x >> 5, c = threadIdx.x & 31;
        int row = rb + r;
        float4 v = (row < nN) ? x4[(size_t)row * 32 + c] : make_float4(0, 0, 0, 0);
        ((float4*)xs[r])[c] = v;
    }
    __syncthreads();
    int r = threadIdx.x >> 5;
    int row = rb + r;
    if (row >= nN) return;
    int j = threadIdx.x & 31;
    float acc = 0.f;
#pragma unroll 8
    for (int k = 0; k < FEAT_IN; ++k) acc = fmaf(xs[r][k], Ws[k * F1 + j], acc);
    float g = acc * dinv[row];
    float other = __shfl_xor(g, 1);
    if ((j & 1) == 0) {
        int c = j >> 4;                       // chunk
        int w = (j & 15) >> 1;                // u32 slot in row
        Gc[((size_t)c * (nN + 1) + row) * 8 + w] = f2bf(g) | (f2bf(other) << 16);
    }
}

// ---------- agg1: ILP-4 gather over chunk, write H chunk (bf16) ----------
__global__ void __launch_bounds__(256)
agg1v2(const int* __restrict__ rowptr, const int* __restrict__ rowend,
       const int* __restrict__ csrP, const unsigned* __restrict__ Gc,
       const float* __restrict__ dinv, const float* __restrict__ b1,
       unsigned* __restrict__ Hc, int nN, int K) {
    int b = blockIdx.x;
    int xcd = b & 7;
    int c = xcd & 1;
    int k = (b >> 3) * 4 + (xcd >> 1);
    if (k >= K) return;
    int t = threadIdx.x, wv = t >> 6, lane = t & 63;
    int node = k * 16 + wv * 4 + (lane >> 4);
    int slot = (lane >> 1) & 7, comp = lane & 1;
    bool vn = node < nN;
    const uint4* Gch = (const uint4*)(Gc + (size_t)c * (nN + 1) * 8);
    float a[8] = {0, 0, 0, 0, 0, 0, 0, 0};
    if (vn) {
        if ((lane & 14) == 0) bfacc8(a, Gch[(size_t)node * 2 + comp]);  // self-loop
        int beg = rowptr[node], endp = rowend[node];
        for (int e = beg + slot * 4; e < endp; e += 32) {
            int4 idx = *(const int4*)(csrP + e);
            uint4 r0 = Gch[(size_t)idx.x * 2 + comp];
            uint4 r1 = Gch[(size_t)idx.y * 2 + comp];
            uint4 r2 = Gch[(size_t)idx.z * 2 + comp];
            uint4 r3 = Gch[(size_t)idx.w * 2 + comp];
            bfacc8(a, r0); bfacc8(a, r1); bfacc8(a, r2); bfacc8(a, r3);
        }
    }
#pragma unroll
    for (int m = 2; m < 16; m <<= 1) {
#pragma unroll
        for (int i = 0; i < 8; ++i) a[i] += __shfl_xor(a[i], m);
    }
    if (vn && (lane & 14) == 0) {
        float dv = dinv[node];
        const float* bb = b1 + c * 16 + comp * 8;
        float h[8];
#pragma unroll
        for (int i = 0; i < 8; ++i) {
            float x1 = fmaxf(fmaf(dv, a[i], bb[i]), 0.f);
            h[i] = dv * x1;
        }
        uint4 hp;
        hp.x = f2bf(h[0]) | (f2bf(h[1]) << 16);
        hp.y = f2bf(h[2]) | (f2bf(h[3]) << 16);
        hp.z = f2bf(h[4]) | (f2bf(h[5]) << 16);
        hp.w = f2bf(h[6]) | (f2bf(h[7]) << 16);
        ((uint4*)(Hc + (size_t)c * (nN + 1) * 8))[(size_t)node * 2 + comp] = hp;
    }
}

// ---------- agg2: ILP-4 gather over H chunk, write A2 fp32 [nN][32] ----------
__global__ void __launch_bounds__(256)
agg2v2(const int* __restrict__ rowptr, const int* __restrict__ rowend,
       const int* __restrict__ csrP, const unsigned* __restrict__ Hc,
       const float* __restrict__ dinv, float* __restrict__ A2, int nN, int K) {
    int b = blockIdx.x;
    int xcd = b & 7;
    int c = xcd & 1;
    int k = (b >> 3) * 4 + (xcd >> 1);
    if (k >= K) return;
    int t = threadIdx.x, wv = t >> 6, lane = t & 63;
    int node = k * 16 + wv * 4 + (lane >> 4);
    int slot = (lane >> 1) & 7, comp = lane & 1;
    bool vn = node < nN;
    const uint4* Hch = (const uint4*)(Hc + (size_t)c * (nN + 1) * 8);
    float a[8] = {0, 0, 0, 0, 0, 0, 0, 0};
    if (vn) {
        if ((lane & 14) == 0) bfacc8(a, Hch[(size_t)node * 2 + comp]);  // self-loop
        int beg = rowptr[node], endp = rowend[node];
        for (int e = beg + slot * 4; e < endp; e += 32) {
            int4 idx = *(const int4*)(csrP + e);
            uint4 r0 = Hch[(size_t)idx.x * 2 + comp];
            uint4 r1 = Hch[(size_t)idx.y * 2 + comp];
            uint4 r2 = Hch[(size_t)idx.z * 2 + comp];
            uint4 r3 = Hch[(size_t)idx.w * 2 + comp];
            bfacc8(a, r0); bfacc8(a, r1); bfacc8(a, r2); bfacc8(a, r3);
        }
    }
#pragma unroll
    for (int m = 2; m < 16; m <<= 1) {
#pragma unroll
        for (int i = 0; i < 8; ++i) a[i] += __shfl_xor(a[i], m);
    }
    if (vn && (lane & 14) == 0) {
        float dv = dinv[node];
        float* dst = A2 + (size_t)node * F1 + c * 16 + comp * 8;
        float4 o0 = make_float4(dv * a[0], dv * a[1], dv * a[2], dv * a[3]);
        float4 o1 = make_float4(dv * a[4], dv * a[5], dv * a[6], dv * a[7]);
        ((float4*)dst)[0] = o0;
        ((float4*)dst)[1] = o1;
    }
}

// ---------- segmented pool of x1 from Hc (batch sorted; flush on graph change) ----------
__global__ void __launch_bounds__(256)
poolX1(const unsigned* __restrict__ Hc, const float* __restrict__ rs,
       const int* __restrict__ batch, float* __restrict__ psum, int nN) {
    int t = threadIdx.x, wv = t >> 6, lane = t & 63;
    int c = wv >> 1, half = wv & 1;
    int base = blockIdx.x * PNPB + half * (PNPB / 2);
    int w32 = lane & 7, noff = lane >> 3;
    const unsigned* Hch = Hc + (size_t)c * (nN + 1) * 8;
    int feat = c * 16 + w32 * 2;
    float a0 = 0.f, a1 = 0.f;
    int curG = -1;
#pragma unroll 4
    for (int i = 0; i < PNPB / 16; ++i) {
        int node = base + noff + 8 * i;
        if (node >= nN) break;
        int bg = batch[node];
        if (bg != curG) {
            if (curG >= 0) {
                atomicAdd(&psum[(size_t)curG * FJ + feat + 0], a0);
                atomicAdd(&psum[(size_t)curG * FJ + feat + 1], a1);
            }
            a0 = a1 = 0.f; curG = bg;
        }
        unsigned v = Hch[(size_t)node * 8 + w32];
        float r = rs[node];
        a0 = fmaf(bf2f(v & 0xffffu), r, a0);
        a1 = fmaf(bf2f(v >> 16), r, a1);
    }
    if (curG >= 0) {
        atomicAdd(&psum[(size_t)curG * FJ + feat + 0], a0);
        atomicAdd(&psum[(size_t)curG * FJ + feat + 1], a1);
    }
}

// ---------- segmented x2 pool: per-node W2 transform + relu, flush on graph change ----------
__global__ void __launch_bounds__(256)
poolX2(const float* __restrict__ A2, const float* __restrict__ W2,
       const float* __restrict__ b2, const int* __restrict__ batch,
       float* __restrict__ psum, int nN) {
    __shared__ float W2s[F1 * F2];
    for (int i = threadIdx.x; i < F1 * F2; i += 256) W2s[i] = W2[i];
    __syncthreads();
    int wv = threadIdx.x >> 6, lane = threadIdx.x & 63;
    int nbase = blockIdx.x * 256 + wv * 64;
    float bj = b2[lane];
    float acc = 0.f;
    int curG = -1;
    for (int i = 0; i < 64; ++i) {
        int node = nbase + i;
        if (node >= nN) break;
        int bg = batch[node];
        if (bg != curG) {
            if (curG >= 0) atomicAdd(&psum[(size_t)curG * FJ + F1 + lane], acc);
            acc = 0.f; curG = bg;
        }
        float av = (lane < F1) ? A2[(size_t)node * F1 + lane] : 0.f;
        float dot = 0.f;
#pragma unroll
        for (int k = 0; k < F1; ++k) dot = fmaf(__shfl(av, k), W2s[k * F2 + lane], dot);
        acc += fmaxf(dot + bj, 0.f);
    }
    if (curG >= 0) atomicAdd(&psum[(size_t)curG * FJ + F1 + lane], acc);
}

// ---------- counts via binary search (batch sorted, no atomics) ----------
__global__ void cntBS(const int* __restrict__ batch, float* __restrict__ cnt,
                      int nN, int nG) {
    int g = blockIdx.x * blockDim.x + threadIdx.x;
    if (g >= nG) return;
    int lo = 0, hi = nN;
    while (lo < hi) { int m = (lo + hi) >> 1; if (batch[m] < g) lo = m + 1; else hi = m; }
    int s = lo;
    lo = 0; hi = nN;
    while (lo < hi) { int m = (lo + hi) >> 1; if (batch[m] < g + 1) lo = m + 1; else hi = m; }
    cnt[g] = (float)(lo - s);
}

__global__ void mlp_kernel(const float* __restrict__ psum, const float* __restrict__ cnt,
                           const float* __restrict__ fW1, const float* __restrict__ fb1,
                           const float* __restrict__ fW2, const float* __restrict__ fb2,
                           float* __restrict__ out) {
    __shared__ float p[FJ];
    __shared__ float red[FH];
    int g = blockIdx.x, tid = threadIdx.x;
    float c = fmaxf(cnt[g], 1.0f);
    if (tid < FJ) p[tid] = psum[g * FJ + tid] / c;
    __syncthreads();
    float acc = fb1[tid];
    for (int k = 0; k < FJ; ++k) acc = fmaf(p[k], fW1[k * FH + tid], acc);
    float h = fmaxf(acc, 0.f);
    red[tid] = h * fW2[tid];
    __syncthreads();
    for (int s = FH / 2; s > 0; s >>= 1) {
        if (tid < s) red[tid] += red[tid + s];
        __syncthreads();
    }
    if (tid == 0) out[g] = red[0] + fb2[0];
}

extern "C" void kernel_launch(void* const* d_in, const int* in_sizes, int n_in,
                              void* d_out, int out_size, void* d_ws, size_t ws_size,
                              hipStream_t stream) {
    const float* x   = (const float*)d_in[0];
    const int*   ei  = (const int*)d_in[1];
    const int*   bat = (const int*)d_in[2];
    const float* W1  = (const float*)d_in[3];
    const float* b1  = (const float*)d_in[4];
    const float* W2  = (const float*)d_in[5];
    const float* b2  = (const float*)d_in[6];
    const float* fW1 = (const float*)d_in[7];
    const float* fb1 = (const float*)d_in[8];
    const float* fW2 = (const float*)d_in[9];
    const float* fb2 = (const float*)d_in[10];
    float* out = (float*)d_out;

    int nN = in_sizes[0] / FEAT_IN;
    int nE = in_sizes[1] / 2;
    int nG = out_size;
    const int* src = ei;
    const int* dst = ei + nE;

    int nB  = (nN + BNODES - 1) >> BSH;
    int nCh = (nE + CH - 1) / CH;
    int K   = (nN + 15) / 16;            // 16 nodes per block (4 waves x 4 nodes)
    int gridC = ((K + 3) / 4) * 8;       // XCD-pinned: 8 blocks cover {2 chunks x 4 k}

    char* w = (char*)d_ws;
    auto alloc = [&](size_t bytes) { char* p = w; w += (bytes + 15) & ~(size_t)15; return p; };
    int*      bcnt   = (int*)alloc(NBMAX * 4);
    int*      boff   = (int*)alloc((NBMAX + 1) * 4);
    int*      bcur   = (int*)alloc(NBMAX * 4);
    unsigned* EB     = (unsigned*)alloc((size_t)nE * 4);
    int*      rowptr = (int*)alloc((size_t)nN * 4);
    int*      rowend = (int*)alloc((size_t)nN * 4);
    int*      csrP   = (int*)alloc(((size_t)nE + (size_t)NBMAX * PADMAX + 64) * 4);
    float*    dinv   = (float*)alloc((size_t)nN * 4);
    float*    rsb    = (float*)alloc((size_t)nN * 4);
    unsigned* Gc     = (unsigned*)alloc((size_t)2 * (nN + 1) * 16 * 2);  // bf16 [2][nN+1][16]
    unsigned* Hc     = (unsigned*)alloc((size_t)2 * (nN + 1) * 16 * 2);
    float*    A2     = (float*)alloc((size_t)nN * F1 * 4);
    float*    psum   = (float*)alloc((size_t)nG * FJ * 4);
    float*    cnt    = (float*)alloc((size_t)nG * 4);

    hipMemsetAsync(bcnt, 0, NBMAX * 4, stream);
    hipMemsetAsync(psum, 0, (size_t)nG * FJ * 4, stream);
    // zero sentinel rows (node nN) of each chunk in Gc and Hc
    for (int c = 0; c < 2; ++c) {
        hipMemsetAsync(Gc + ((size_t)c * (nN + 1) + nN) * 16, 0, 32, stream);
        hipMemsetAsync(Hc + ((size_t)c * (nN + 1) + nN) * 16, 0, 32, stream);
    }

    // CSR build (padded) via dst-buckets
    histA<<<1024, 256, 0, stream>>>(dst, bcnt, nE, nB);
    scanBk<<<1, 256, 0, stream>>>(bcnt, boff, bcur, nB, nE);
    scatterEB<<<nCh, 256, 0, stream>>>(src, dst, bcur, EB, nE, nB);
    bucketSortK<<<nB, 256, 0, stream>>>(EB, boff, rowptr, rowend, csrP, dinv, rsb, nN, nB);

    // layer 1
    gemm1_kernel<<<(nN + 7) / 8, 256, 0, stream>>>((const float4*)x, W1, dinv, Gc, nN);
    agg1v2<<<gridC, 256, 0, stream>>>(rowptr, rowend, csrP, Gc, dinv, b1, Hc, nN, K);
    // layer 2
    agg2v2<<<gridC, 256, 0, stream>>>(rowptr, rowend, csrP, Hc, dinv, A2, nN, K);

    // segmented pooling + counts + MLP
    poolX1<<<(nN + PNPB - 1) / PNPB, 256, 0, stream>>>(Hc, rsb, bat, psum, nN);
    poolX2<<<(nN + 255) / 256, 256, 0, stream>>>(A2, W2, b2, bat, psum, nN);
    cntBS<<<(nG + 255) / 256, 256, 0, stream>>>(bat, cnt, nN, nG);
    mlp_kernel<<<nG, FH, 0, stream>>>(psum, cnt, fW1, fb1, fW2, fb2, out);
}

// Round 12
// 296.386 us; speedup vs baseline: 2.2371x; 1.2079x over previous
//
#include <hip/hip_runtime.h>
#include <stdint.h>

#define FEAT_IN 128
#define F1 32
#define F2 64
#define FJ 96
#define FH 128

#define BSH 8                  // 256 nodes per bucket
#define BNODES 256
#define NBMAX 512
#define CH 8192
#define SRCBITS 17             // nN must be < 2^17
#define SRCMASK 0x1FFFFu
#define PADMAX 768             // max pad per bucket (256 nodes * 3)
#define PNPB 256               // nodes per block in poolX1 (was 1024: 4x TLP)
#define NP2 64                 // nodes per block in poolX2

__device__ __forceinline__ unsigned f2bf(float f) {
    unsigned u = __float_as_uint(f);
    return (u + 0x7FFFu + ((u >> 16) & 1u)) >> 16;   // RNE
}
__device__ __forceinline__ float bf2f(unsigned h) { return __uint_as_float(h << 16); }
__device__ __forceinline__ void bfacc8(float* a, uint4 v) {
    a[0] += bf2f(v.x & 0xffffu); a[1] += bf2f(v.x >> 16);
    a[2] += bf2f(v.y & 0xffffu); a[3] += bf2f(v.y >> 16);
    a[4] += bf2f(v.z & 0xffffu); a[5] += bf2f(v.z >> 16);
    a[6] += bf2f(v.w & 0xffffu); a[7] += bf2f(v.w >> 16);
}

// ---------- bucket histogram ----------
__global__ void histA(const int* __restrict__ dst, int* __restrict__ bcnt, int nE, int nB) {
    __shared__ int h[NBMAX];
    for (int t = threadIdx.x; t < nB; t += blockDim.x) h[t] = 0;
    __syncthreads();
    int stride = gridDim.x * blockDim.x;
    for (int e = blockIdx.x * blockDim.x + threadIdx.x; e < nE; e += stride)
        atomicAdd(&h[dst[e] >> BSH], 1);
    __syncthreads();
    for (int t = threadIdx.x; t < nB; t += blockDim.x)
        if (h[t]) atomicAdd(&bcnt[t], h[t]);
}

// ---------- scan buckets ----------
__global__ void scanBk(const int* __restrict__ bcnt, int* __restrict__ boff,
                       int* __restrict__ bcur, int nB, int nE) {
    __shared__ int ps[256];
    int t = threadIdx.x;
    int c[4]; int s = 0;
#pragma unroll
    for (int k = 0; k < 4; ++k) { int b = t * 4 + k; c[k] = (b < nB) ? bcnt[b] : 0; s += c[k]; }
    ps[t] = s; __syncthreads();
    for (int off = 1; off < 256; off <<= 1) {
        int v = (t >= off) ? ps[t - off] : 0; __syncthreads();
        ps[t] += v; __syncthreads();
    }
    int excl = ps[t] - s;
#pragma unroll
    for (int k = 0; k < 4; ++k) {
        int b = t * 4 + k;
        if (b < nB) { boff[b] = excl; bcur[b] = excl; excl += c[k]; }
    }
    if (t == 255) boff[nB] = nE;
}

// ---------- scatter edges into buckets, LDS-staged ----------
__global__ void scatterEB(const int* __restrict__ src, const int* __restrict__ dst,
                          int* __restrict__ bcur, unsigned* __restrict__ EB, int nE, int nB) {
    __shared__ int h[NBMAX], loff[NBMAX], gbase[NBMAX], lcur[NBMAX];
    __shared__ int ps[256];
    __shared__ uint2 stage[CH];
    int t = threadIdx.x;
    int e0 = blockIdx.x * CH;
    int ecnt = min(CH, nE - e0);
    if (ecnt <= 0) return;
    for (int i = t; i < nB; i += 256) h[i] = 0;
    __syncthreads();
    for (int i = t; i < ecnt; i += 256) atomicAdd(&h[dst[e0 + i] >> BSH], 1);
    __syncthreads();
    int b0 = 2 * t, b1 = 2 * t + 1;
    int c0 = (b0 < nB) ? h[b0] : 0;
    int c1 = (b1 < nB) ? h[b1] : 0;
    ps[t] = c0 + c1; __syncthreads();
    for (int off = 1; off < 256; off <<= 1) {
        int v = (t >= off) ? ps[t - off] : 0; __syncthreads();
        ps[t] += v; __syncthreads();
    }
    int excl = ps[t] - (c0 + c1);
    if (b0 < nB) { loff[b0] = excl;      lcur[b0] = excl; }
    if (b1 < nB) { loff[b1] = excl + c0; lcur[b1] = excl + c0; }
    __syncthreads();
    for (int i = t; i < nB; i += 256)
        if (h[i]) gbase[i] = atomicAdd(&bcur[i], h[i]);
    __syncthreads();
    for (int i = t; i < ecnt; i += 256) {
        int d = dst[e0 + i], s = src[e0 + i];
        int b = d >> BSH;
        int p = atomicAdd(&lcur[b], 1);
        stage[p] = make_uint2((unsigned)s, (unsigned)d);
    }
    __syncthreads();
    for (int i = t; i < ecnt; i += 256) {
        uint2 v = stage[i];
        int bb = (int)(v.y >> BSH);
        EB[gbase[bb] + (i - loff[bb])] = v.x | ((v.y & (BNODES - 1)) << SRCBITS);
    }
}

// ---------- per-bucket counting sort -> PADDED csr (x4, sentinel nN), dinv, rs ----------
__global__ void __launch_bounds__(256)
bucketSortK(const unsigned* __restrict__ EB, const int* __restrict__ boff,
            int* __restrict__ rowptr, int* __restrict__ rowend, int* __restrict__ csrP,
            float* __restrict__ dinv, float* __restrict__ rs, int nN, int nB) {
    __shared__ int hist[BNODES];
    __shared__ int cur[BNODES];
    __shared__ int ps[256];
    int b = blockIdx.x, t = threadIdx.x;
    int beg = boff[b], end = boff[b + 1];
    hist[t] = 0;
    __syncthreads();
    for (int i = beg + t; i < end; i += 256) atomicAdd(&hist[EB[i] >> SRCBITS], 1);
    __syncthreads();
    int deg = hist[t];
    int pdeg = (deg + 3) & ~3;
    ps[t] = pdeg; __syncthreads();
    for (int off = 1; off < 256; off <<= 1) {
        int v = (t >= off) ? ps[t - off] : 0; __syncthreads();
        ps[t] += v; __syncthreads();
    }
    int base = ((beg + 3) & ~3) + b * PADMAX;
    int excl = base + ps[t] - pdeg;
    int node = (b << BSH) + t;
    if (node < nN) {
        rowptr[node] = excl;
        rowend[node] = excl + pdeg;
        dinv[node] = rsqrtf((float)deg + 1.0f);
        rs[node] = sqrtf((float)deg + 1.0f);
    }
    cur[t] = excl;
    __syncthreads();
    for (int i = beg + t; i < end; i += 256) {
        unsigned v = EB[i];
        int p = atomicAdd(&cur[v >> SRCBITS], 1);
        csrP[p] = (int)(v & SRCMASK);
    }
    __syncthreads();
    // fill sentinel pads (<=3 per node)
    for (int p = cur[t]; p < excl + pdeg; ++p) csrP[p] = nN;
}

// ---------- g1 = bf16((x @ W1) * dinv), chunked [2][nN+1][16] ----------
__global__ void gemm1_kernel(const float4* __restrict__ x4, const float* __restrict__ W1,
                             const float* __restrict__ dinv, unsigned* __restrict__ Gc,
                             int nN) {
    __shared__ float Ws[FEAT_IN * F1];
    __shared__ float xs[8][FEAT_IN];
    for (int t = threadIdx.x; t < FEAT_IN * F1; t += 256) Ws[t] = W1[t];
    int rb = blockIdx.x * 8;
    {
        int r = threadIdx.x >> 5, c = threadIdx.x & 31;
        int row = rb + r;
        float4 v = (row < nN) ? x4[(size_t)row * 32 + c] : make_float4(0, 0, 0, 0);
        ((float4*)xs[r])[c] = v;
    }
    __syncthreads();
    int r = threadIdx.x >> 5;
    int row = rb + r;
    if (row >= nN) return;
    int j = threadIdx.x & 31;
    float acc = 0.f;
#pragma unroll 8
    for (int k = 0; k < FEAT_IN; ++k) acc = fmaf(xs[r][k], Ws[k * F1 + j], acc);
    float g = acc * dinv[row];
    float other = __shfl_xor(g, 1);
    if ((j & 1) == 0) {
        int c = j >> 4;                       // chunk
        int w = (j & 15) >> 1;                // u32 slot in row
        Gc[((size_t)c * (nN + 1) + row) * 8 + w] = f2bf(g) | (f2bf(other) << 16);
    }
}

// ---------- agg1: ILP-4 gather over chunk, write H chunk (bf16) ----------
__global__ void __launch_bounds__(256)
agg1v2(const int* __restrict__ rowptr, const int* __restrict__ rowend,
       const int* __restrict__ csrP, const unsigned* __restrict__ Gc,
       const float* __restrict__ dinv, const float* __restrict__ b1,
       unsigned* __restrict__ Hc, int nN, int K) {
    int b = blockIdx.x;
    int xcd = b & 7;
    int c = xcd & 1;
    int k = (b >> 3) * 4 + (xcd >> 1);
    if (k >= K) return;
    int t = threadIdx.x, wv = t >> 6, lane = t & 63;
    int node = k * 16 + wv * 4 + (lane >> 4);
    int slot = (lane >> 1) & 7, comp = lane & 1;
    bool vn = node < nN;
    const uint4* Gch = (const uint4*)(Gc + (size_t)c * (nN + 1) * 8);
    float a[8] = {0, 0, 0, 0, 0, 0, 0, 0};
    if (vn) {
        if ((lane & 14) == 0) bfacc8(a, Gch[(size_t)node * 2 + comp]);  // self-loop
        int beg = rowptr[node], endp = rowend[node];
        for (int e = beg + slot * 4; e < endp; e += 32) {
            int4 idx = *(const int4*)(csrP + e);
            uint4 r0 = Gch[(size_t)idx.x * 2 + comp];
            uint4 r1 = Gch[(size_t)idx.y * 2 + comp];
            uint4 r2 = Gch[(size_t)idx.z * 2 + comp];
            uint4 r3 = Gch[(size_t)idx.w * 2 + comp];
            bfacc8(a, r0); bfacc8(a, r1); bfacc8(a, r2); bfacc8(a, r3);
        }
    }
#pragma unroll
    for (int m = 2; m < 16; m <<= 1) {
#pragma unroll
        for (int i = 0; i < 8; ++i) a[i] += __shfl_xor(a[i], m);
    }
    if (vn && (lane & 14) == 0) {
        float dv = dinv[node];
        const float* bb = b1 + c * 16 + comp * 8;
        float h[8];
#pragma unroll
        for (int i = 0; i < 8; ++i) {
            float x1 = fmaxf(fmaf(dv, a[i], bb[i]), 0.f);
            h[i] = dv * x1;
        }
        uint4 hp;
        hp.x = f2bf(h[0]) | (f2bf(h[1]) << 16);
        hp.y = f2bf(h[2]) | (f2bf(h[3]) << 16);
        hp.z = f2bf(h[4]) | (f2bf(h[5]) << 16);
        hp.w = f2bf(h[6]) | (f2bf(h[7]) << 16);
        ((uint4*)(Hc + (size_t)c * (nN + 1) * 8))[(size_t)node * 2 + comp] = hp;
    }
}

// ---------- agg2: ILP-4 gather over H chunk, write A2 fp32 [nN][32] ----------
__global__ void __launch_bounds__(256)
agg2v2(const int* __restrict__ rowptr, const int* __restrict__ rowend,
       const int* __restrict__ csrP, const unsigned* __restrict__ Hc,
       const float* __restrict__ dinv, float* __restrict__ A2, int nN, int K) {
    int b = blockIdx.x;
    int xcd = b & 7;
    int c = xcd & 1;
    int k = (b >> 3) * 4 + (xcd >> 1);
    if (k >= K) return;
    int t = threadIdx.x, wv = t >> 6, lane = t & 63;
    int node = k * 16 + wv * 4 + (lane >> 4);
    int slot = (lane >> 1) & 7, comp = lane & 1;
    bool vn = node < nN;
    const uint4* Hch = (const uint4*)(Hc + (size_t)c * (nN + 1) * 8);
    float a[8] = {0, 0, 0, 0, 0, 0, 0, 0};
    if (vn) {
        if ((lane & 14) == 0) bfacc8(a, Hch[(size_t)node * 2 + comp]);  // self-loop
        int beg = rowptr[node], endp = rowend[node];
        for (int e = beg + slot * 4; e < endp; e += 32) {
            int4 idx = *(const int4*)(csrP + e);
            uint4 r0 = Hch[(size_t)idx.x * 2 + comp];
            uint4 r1 = Hch[(size_t)idx.y * 2 + comp];
            uint4 r2 = Hch[(size_t)idx.z * 2 + comp];
            uint4 r3 = Hch[(size_t)idx.w * 2 + comp];
            bfacc8(a, r0); bfacc8(a, r1); bfacc8(a, r2); bfacc8(a, r3);
        }
    }
#pragma unroll
    for (int m = 2; m < 16; m <<= 1) {
#pragma unroll
        for (int i = 0; i < 8; ++i) a[i] += __shfl_xor(a[i], m);
    }
    if (vn && (lane & 14) == 0) {
        float dv = dinv[node];
        float* dst = A2 + (size_t)node * F1 + c * 16 + comp * 8;
        float4 o0 = make_float4(dv * a[0], dv * a[1], dv * a[2], dv * a[3]);
        float4 o1 = make_float4(dv * a[4], dv * a[5], dv * a[6], dv * a[7]);
        ((float4*)dst)[0] = o0;
        ((float4*)dst)[1] = o1;
    }
}

// ---------- segmented pool of x1 from Hc (batch sorted; flush on graph change) ----------
__global__ void __launch_bounds__(256)
poolX1(const unsigned* __restrict__ Hc, const float* __restrict__ rs,
       const int* __restrict__ batch, float* __restrict__ psum, int nN) {
    int t = threadIdx.x, wv = t >> 6, lane = t & 63;
    int c = wv >> 1, half = wv & 1;
    int base = blockIdx.x * PNPB + half * (PNPB / 2);
    int w32 = lane & 7, noff = lane >> 3;
    const unsigned* Hch = Hc + (size_t)c * (nN + 1) * 8;
    int feat = c * 16 + w32 * 2;
    float a0 = 0.f, a1 = 0.f;
    int curG = -1;
#pragma unroll 4
    for (int i = 0; i < PNPB / 16; ++i) {
        int node = base + noff + 8 * i;
        if (node >= nN) break;
        int bg = batch[node];
        if (bg != curG) {
            if (curG >= 0) {
                atomicAdd(&psum[(size_t)curG * FJ + feat + 0], a0);
                atomicAdd(&psum[(size_t)curG * FJ + feat + 1], a1);
            }
            a0 = a1 = 0.f; curG = bg;
        }
        unsigned v = Hch[(size_t)node * 8 + w32];
        float r = rs[node];
        a0 = fmaf(bf2f(v & 0xffffu), r, a0);
        a1 = fmaf(bf2f(v >> 16), r, a1);
    }
    if (curG >= 0) {
        atomicAdd(&psum[(size_t)curG * FJ + feat + 0], a0);
        atomicAdd(&psum[(size_t)curG * FJ + feat + 1], a1);
    }
}

// ---------- segmented x2 pool v2: LDS-staged A2, 16 nodes/wave ----------
__global__ void __launch_bounds__(256)
poolX2(const float* __restrict__ A2, const float* __restrict__ W2,
       const float* __restrict__ b2, const int* __restrict__ batch,
       float* __restrict__ psum, int nN) {
    __shared__ float W2s[F1 * F2];      // 8 KB
    __shared__ float aL[NP2][F1];       // 8 KB
    int t = threadIdx.x;
    for (int i = t; i < F1 * F2; i += 256) W2s[i] = W2[i];
    int nbase = blockIdx.x * NP2;
    {
        const float4* A4 = (const float4*)(A2 + (size_t)nbase * F1);
        float4* aL4 = (float4*)aL;
        int total4 = NP2 * F1 / 4;      // 512
        for (int i = t; i < total4; i += 256) {
            int gnode = nbase + (i >> 3);
            aL4[i] = (gnode < nN) ? A4[i] : make_float4(0.f, 0.f, 0.f, 0.f);
        }
    }
    __syncthreads();
    int wv = t >> 6, lane = t & 63;
    int n0 = wv * (NP2 / 4);
    float bj = b2[lane];
    float acc = 0.f;
    int curG = -1;
    for (int i = 0; i < NP2 / 4; ++i) {
        int node = nbase + n0 + i;
        if (node >= nN) break;
        int bg = batch[node];
        if (bg != curG) {
            if (curG >= 0) atomicAdd(&psum[(size_t)curG * FJ + F1 + lane], acc);
            acc = 0.f; curG = bg;
        }
        const float* a = aL[n0 + i];
        float dot = 0.f;
#pragma unroll
        for (int k = 0; k < F1; ++k) dot = fmaf(a[k], W2s[k * F2 + lane], dot);
        acc += fmaxf(dot + bj, 0.f);
    }
    if (curG >= 0) atomicAdd(&psum[(size_t)curG * FJ + F1 + lane], acc);
}

// ---------- counts via binary search (batch sorted, no atomics) ----------
__global__ void cntBS(const int* __restrict__ batch, float* __restrict__ cnt,
                      int nN, int nG) {
    int g = blockIdx.x * blockDim.x + threadIdx.x;
    if (g >= nG) return;
    int lo = 0, hi = nN;
    while (lo < hi) { int m = (lo + hi) >> 1; if (batch[m] < g) lo = m + 1; else hi = m; }
    int s = lo;
    lo = 0; hi = nN;
    while (lo < hi) { int m = (lo + hi) >> 1; if (batch[m] < g + 1) lo = m + 1; else hi = m; }
    cnt[g] = (float)(lo - s);
}

__global__ void mlp_kernel(const float* __restrict__ psum, const float* __restrict__ cnt,
                           const float* __restrict__ fW1, const float* __restrict__ fb1,
                           const float* __restrict__ fW2, const float* __restrict__ fb2,
                           float* __restrict__ out) {
    __shared__ float p[FJ];
    __shared__ float red[FH];
    int g = blockIdx.x, tid = threadIdx.x;
    float c = fmaxf(cnt[g], 1.0f);
    if (tid < FJ) p[tid] = psum[g * FJ + tid] / c;
    __syncthreads();
    float acc = fb1[tid];
    for (int k = 0; k < FJ; ++k) acc = fmaf(p[k], fW1[k * FH + tid], acc);
    float h = fmaxf(acc, 0.f);
    red[tid] = h * fW2[tid];
    __syncthreads();
    for (int s = FH / 2; s > 0; s >>= 1) {
        if (tid < s) red[tid] += red[tid + s];
        __syncthreads();
    }
    if (tid == 0) out[g] = red[0] + fb2[0];
}

extern "C" void kernel_launch(void* const* d_in, const int* in_sizes, int n_in,
                              void* d_out, int out_size, void* d_ws, size_t ws_size,
                              hipStream_t stream) {
    const float* x   = (const float*)d_in[0];
    const int*   ei  = (const int*)d_in[1];
    const int*   bat = (const int*)d_in[2];
    const float* W1  = (const float*)d_in[3];
    const float* b1  = (const float*)d_in[4];
    const float* W2  = (const float*)d_in[5];
    const float* b2  = (const float*)d_in[6];
    const float* fW1 = (const float*)d_in[7];
    const float* fb1 = (const float*)d_in[8];
    const float* fW2 = (const float*)d_in[9];
    const float* fb2 = (const float*)d_in[10];
    float* out = (float*)d_out;

    int nN = in_sizes[0] / FEAT_IN;
    int nE = in_sizes[1] / 2;
    int nG = out_size;
    const int* src = ei;
    const int* dst = ei + nE;

    int nB  = (nN + BNODES - 1) >> BSH;
    int nCh = (nE + CH - 1) / CH;
    int K   = (nN + 15) / 16;            // 16 nodes per block (4 waves x 4 nodes)
    int gridC = ((K + 3) / 4) * 8;       // XCD-pinned: 8 blocks cover {2 chunks x 4 k}

    char* w = (char*)d_ws;
    auto alloc = [&](size_t bytes) { char* p = w; w += (bytes + 15) & ~(size_t)15; return p; };
    int*      bcnt   = (int*)alloc(NBMAX * 4);
    int*      boff   = (int*)alloc((NBMAX + 1) * 4);
    int*      bcur   = (int*)alloc(NBMAX * 4);
    unsigned* EB     = (unsigned*)alloc((size_t)nE * 4);
    int*      rowptr = (int*)alloc((size_t)nN * 4);
    int*      rowend = (int*)alloc((size_t)nN * 4);
    int*      csrP   = (int*)alloc(((size_t)nE + (size_t)NBMAX * PADMAX + 64) * 4);
    float*    dinv   = (float*)alloc((size_t)nN * 4);
    float*    rsb    = (float*)alloc((size_t)nN * 4);
    unsigned* Gc     = (unsigned*)alloc((size_t)2 * (nN + 1) * 16 * 2);  // bf16 [2][nN+1][16]
    unsigned* Hc     = (unsigned*)alloc((size_t)2 * (nN + 1) * 16 * 2);
    float*    A2     = (float*)alloc((size_t)(nN + NP2) * F1 * 4);
    float*    psum   = (float*)alloc((size_t)nG * FJ * 4);
    float*    cnt    = (float*)alloc((size_t)nG * 4);

    hipMemsetAsync(bcnt, 0, NBMAX * 4, stream);
    hipMemsetAsync(psum, 0, (size_t)nG * FJ * 4, stream);
    // zero sentinel rows (node nN) of each chunk in Gc and Hc
    for (int c = 0; c < 2; ++c) {
        hipMemsetAsync(Gc + ((size_t)c * (nN + 1) + nN) * 16, 0, 32, stream);
        hipMemsetAsync(Hc + ((size_t)c * (nN + 1) + nN) * 16, 0, 32, stream);
    }

    // CSR build (padded) via dst-buckets
    histA<<<1024, 256, 0, stream>>>(dst, bcnt, nE, nB);
    scanBk<<<1, 256, 0, stream>>>(bcnt, boff, bcur, nB, nE);
    scatterEB<<<nCh, 256, 0, stream>>>(src, dst, bcur, EB, nE, nB);
    bucketSortK<<<nB, 256, 0, stream>>>(EB, boff, rowptr, rowend, csrP, dinv, rsb, nN, nB);

    // layer 1
    gemm1_kernel<<<(nN + 7) / 8, 256, 0, stream>>>((const float4*)x, W1, dinv, Gc, nN);
    agg1v2<<<gridC, 256, 0, stream>>>(rowptr, rowend, csrP, Gc, dinv, b1, Hc, nN, K);
    // layer 2
    agg2v2<<<gridC, 256, 0, stream>>>(rowptr, rowend, csrP, Hc, dinv, A2, nN, K);

    // segmented pooling + counts + MLP
    poolX1<<<(nN + PNPB - 1) / PNPB, 256, 0, stream>>>(Hc, rsb, bat, psum, nN);
    poolX2<<<(nN + NP2 - 1) / NP2, 256, 0, stream>>>(A2, W2, b2, bat, psum, nN);
    cntBS<<<(nG + 255) / 256, 256, 0, stream>>>(bat, cnt, nN, nG);
    mlp_kernel<<<nG, FH, 0, stream>>>(psum, cnt, fW1, fb1, fW2, fb2, out);
}

// Round 14
// 280.493 us; speedup vs baseline: 2.3639x; 1.0567x over previous
//
#include <hip/hip_runtime.h>
#include <stdint.h>

#define FEAT_IN 128
#define F1 32
#define F2 64
#define FJ 96
#define FH 128

#define BSH 8                  // 256 nodes per bucket
#define BNODES 256
#define NBMAX 512
#define CH 8192
#define SRCBITS 17             // nN must be < 2^17
#define SRCMASK 0x1FFFFu
#define PADMAX 768             // max pad per bucket (256 nodes * 3)
#define PNPB 256               // nodes per block in poolX1
#define NP2 64                 // nodes per block in poolX2
#define GR 64                  // rows per block in gemm1v3
#define XPAD 132               // padded LDS row stride (floats) for x tile

__device__ __forceinline__ unsigned f2bf(float f) {
    unsigned u = __float_as_uint(f);
    return (u + 0x7FFFu + ((u >> 16) & 1u)) >> 16;   // RNE
}
__device__ __forceinline__ float bf2f(unsigned h) { return __uint_as_float(h << 16); }
__device__ __forceinline__ void bfacc8(float* a, uint4 v) {
    a[0] += bf2f(v.x & 0xffffu); a[1] += bf2f(v.x >> 16);
    a[2] += bf2f(v.y & 0xffffu); a[3] += bf2f(v.y >> 16);
    a[4] += bf2f(v.z & 0xffffu); a[5] += bf2f(v.z >> 16);
    a[6] += bf2f(v.w & 0xffffu); a[7] += bf2f(v.w >> 16);
}
// inline fn, NOT a macro ("w" macro param collides with .w member token)
__device__ __forceinline__ void fma4(float* acc, float s, float4 wv) {
    acc[0] = fmaf(s, wv.x, acc[0]);
    acc[1] = fmaf(s, wv.y, acc[1]);
    acc[2] = fmaf(s, wv.z, acc[2]);
    acc[3] = fmaf(s, wv.w, acc[3]);
}

// ---------- bucket histogram ----------
__global__ void histA(const int* __restrict__ dst, int* __restrict__ bcnt, int nE, int nB) {
    __shared__ int h[NBMAX];
    for (int t = threadIdx.x; t < nB; t += blockDim.x) h[t] = 0;
    __syncthreads();
    int stride = gridDim.x * blockDim.x;
    for (int e = blockIdx.x * blockDim.x + threadIdx.x; e < nE; e += stride)
        atomicAdd(&h[dst[e] >> BSH], 1);
    __syncthreads();
    for (int t = threadIdx.x; t < nB; t += blockDim.x)
        if (h[t]) atomicAdd(&bcnt[t], h[t]);
}

// ---------- scan buckets ----------
__global__ void scanBk(const int* __restrict__ bcnt, int* __restrict__ boff,
                       int* __restrict__ bcur, int nB, int nE) {
    __shared__ int ps[256];
    int t = threadIdx.x;
    int c[4]; int s = 0;
#pragma unroll
    for (int k = 0; k < 4; ++k) { int b = t * 4 + k; c[k] = (b < nB) ? bcnt[b] : 0; s += c[k]; }
    ps[t] = s; __syncthreads();
    for (int off = 1; off < 256; off <<= 1) {
        int v = (t >= off) ? ps[t - off] : 0; __syncthreads();
        ps[t] += v; __syncthreads();
    }
    int excl = ps[t] - s;
#pragma unroll
    for (int k = 0; k < 4; ++k) {
        int b = t * 4 + k;
        if (b < nB) { boff[b] = excl; bcur[b] = excl; excl += c[k]; }
    }
    if (t == 255) boff[nB] = nE;
}

// ---------- scatter edges into buckets, LDS-staged ----------
__global__ void scatterEB(const int* __restrict__ src, const int* __restrict__ dst,
                          int* __restrict__ bcur, unsigned* __restrict__ EB, int nE, int nB) {
    __shared__ int h[NBMAX], loff[NBMAX], gbase[NBMAX], lcur[NBMAX];
    __shared__ int ps[256];
    __shared__ uint2 stage[CH];
    int t = threadIdx.x;
    int e0 = blockIdx.x * CH;
    int ecnt = min(CH, nE - e0);
    if (ecnt <= 0) return;
    for (int i = t; i < nB; i += 256) h[i] = 0;
    __syncthreads();
    for (int i = t; i < ecnt; i += 256) atomicAdd(&h[dst[e0 + i] >> BSH], 1);
    __syncthreads();
    int b0 = 2 * t, b1 = 2 * t + 1;
    int c0 = (b0 < nB) ? h[b0] : 0;
    int c1 = (b1 < nB) ? h[b1] : 0;
    ps[t] = c0 + c1; __syncthreads();
    for (int off = 1; off < 256; off <<= 1) {
        int v = (t >= off) ? ps[t - off] : 0; __syncthreads();
        ps[t] += v; __syncthreads();
    }
    int excl = ps[t] - (c0 + c1);
    if (b0 < nB) { loff[b0] = excl;      lcur[b0] = excl; }
    if (b1 < nB) { loff[b1] = excl + c0; lcur[b1] = excl + c0; }
    __syncthreads();
    for (int i = t; i < nB; i += 256)
        if (h[i]) gbase[i] = atomicAdd(&bcur[i], h[i]);
    __syncthreads();
    for (int i = t; i < ecnt; i += 256) {
        int d = dst[e0 + i], s = src[e0 + i];
        int b = d >> BSH;
        int p = atomicAdd(&lcur[b], 1);
        stage[p] = make_uint2((unsigned)s, (unsigned)d);
    }
    __syncthreads();
    for (int i = t; i < ecnt; i += 256) {
        uint2 v = stage[i];
        int bb = (int)(v.y >> BSH);
        EB[gbase[bb] + (i - loff[bb])] = v.x | ((v.y & (BNODES - 1)) << SRCBITS);
    }
}

// ---------- per-bucket counting sort -> PADDED csr (x4, sentinel nN), dinv, rs ----------
__global__ void __launch_bounds__(256)
bucketSortK(const unsigned* __restrict__ EB, const int* __restrict__ boff,
            int* __restrict__ rowptr, int* __restrict__ rowend, int* __restrict__ csrP,
            float* __restrict__ dinv, float* __restrict__ rs, int nN, int nB) {
    __shared__ int hist[BNODES];
    __shared__ int cur[BNODES];
    __shared__ int ps[256];
    int b = blockIdx.x, t = threadIdx.x;
    int beg = boff[b], end = boff[b + 1];
    hist[t] = 0;
    __syncthreads();
    for (int i = beg + t; i < end; i += 256) atomicAdd(&hist[EB[i] >> SRCBITS], 1);
    __syncthreads();
    int deg = hist[t];
    int pdeg = (deg + 3) & ~3;
    ps[t] = pdeg; __syncthreads();
    for (int off = 1; off < 256; off <<= 1) {
        int v = (t >= off) ? ps[t - off] : 0; __syncthreads();
        ps[t] += v; __syncthreads();
    }
    int base = ((beg + 3) & ~3) + b * PADMAX;
    int excl = base + ps[t] - pdeg;
    int node = (b << BSH) + t;
    if (node < nN) {
        rowptr[node] = excl;
        rowend[node] = excl + pdeg;
        dinv[node] = rsqrtf((float)deg + 1.0f);
        rs[node] = sqrtf((float)deg + 1.0f);
    }
    cur[t] = excl;
    __syncthreads();
    for (int i = beg + t; i < end; i += 256) {
        unsigned v = EB[i];
        int p = atomicAdd(&cur[v >> SRCBITS], 1);
        csrP[p] = (int)(v & SRCMASK);
    }
    __syncthreads();
    // fill sentinel pads (<=3 per node)
    for (int p = cur[t]; p < excl + pdeg; ++p) csrP[p] = nN;
}

// ---------- gemm1 v3: 2x4 register tile, 64 rows/block ----------
__global__ void __launch_bounds__(256)
gemm1v3(const float4* __restrict__ x4, const float* __restrict__ W1,
        const float* __restrict__ dinv, unsigned* __restrict__ Gc, int nN) {
    __shared__ float Ws[FEAT_IN * F1];   // 16 KB
    __shared__ float xs[GR * XPAD];      // 33 KB, stride 132 (16B-aligned, low conflicts)
    int t = threadIdx.x;
    for (int i = t; i < FEAT_IN * F1; i += 256) Ws[i] = W1[i];
    int rb = blockIdx.x * GR;
    for (int i = t; i < GR * 32; i += 256) {
        int r = i >> 5, c = i & 31;
        int row = rb + r;
        float4 v = (row < nN) ? x4[(size_t)row * 32 + c] : make_float4(0.f, 0.f, 0.f, 0.f);
        *(float4*)(xs + r * XPAD + c * 4) = v;
    }
    __syncthreads();
    int cg = t & 7, rg = t >> 3;         // 8 colgroups x 32 rowgroups
    int r0 = rg * 2, r1 = r0 + 1;
    int j0 = cg * 4;
    float acc0[4] = {0.f, 0.f, 0.f, 0.f};
    float acc1[4] = {0.f, 0.f, 0.f, 0.f};
    const float4* xa4 = (const float4*)(xs + r0 * XPAD);
    const float4* xb4 = (const float4*)(xs + r1 * XPAD);
    const float4* W4 = (const float4*)Ws;    // row k = 8 float4; ours at +cg
#pragma unroll 4
    for (int kc = 0; kc < 32; ++kc) {
        float4 xa = xa4[kc];
        float4 xb = xb4[kc];
        float4 w0 = W4[(4 * kc + 0) * 8 + cg];
        float4 w1 = W4[(4 * kc + 1) * 8 + cg];
        float4 w2 = W4[(4 * kc + 2) * 8 + cg];
        float4 w3 = W4[(4 * kc + 3) * 8 + cg];
        fma4(acc0, xa.x, w0); fma4(acc0, xa.y, w1);
        fma4(acc0, xa.z, w2); fma4(acc0, xa.w, w3);
        fma4(acc1, xb.x, w0); fma4(acc1, xb.y, w1);
        fma4(acc1, xb.z, w2); fma4(acc1, xb.w, w3);
    }
    int c = j0 >> 4;                     // chunk
    int w = (j0 & 15) >> 1;              // u32 slot (even)
    int row0 = rb + r0, row1 = rb + r1;
    if (row0 < nN) {
        float dv = dinv[row0];
        uint2 val;
        val.x = f2bf(acc0[0] * dv) | (f2bf(acc0[1] * dv) << 16);
        val.y = f2bf(acc0[2] * dv) | (f2bf(acc0[3] * dv) << 16);
        *(uint2*)(Gc + ((size_t)c * (nN + 1) + row0) * 8 + w) = val;
    }
    if (row1 < nN) {
        float dv = dinv[row1];
        uint2 val;
        val.x = f2bf(acc1[0] * dv) | (f2bf(acc1[1] * dv) << 16);
        val.y = f2bf(acc1[2] * dv) | (f2bf(acc1[3] * dv) << 16);
        *(uint2*)(Gc + ((size_t)c * (nN + 1) + row1) * 8 + w) = val;
    }
}

// ---------- agg1: ILP-4 gather over chunk, write H chunk (bf16) ----------
__global__ void __launch_bounds__(256)
agg1v2(const int* __restrict__ rowptr, const int* __restrict__ rowend,
       const int* __restrict__ csrP, const unsigned* __restrict__ Gc,
       const float* __restrict__ dinv, const float* __restrict__ b1,
       unsigned* __restrict__ Hc, int nN, int K) {
    int b = blockIdx.x;
    int xcd = b & 7;
    int c = xcd & 1;
    int k = (b >> 3) * 4 + (xcd >> 1);
    if (k >= K) return;
    int t = threadIdx.x, wv = t >> 6, lane = t & 63;
    int node = k * 16 + wv * 4 + (lane >> 4);
    int slot = (lane >> 1) & 7, comp = lane & 1;
    bool vn = node < nN;
    const uint4* Gch = (const uint4*)(Gc + (size_t)c * (nN + 1) * 8);
    float a[8] = {0, 0, 0, 0, 0, 0, 0, 0};
    if (vn) {
        if ((lane & 14) == 0) bfacc8(a, Gch[(size_t)node * 2 + comp]);  // self-loop
        int beg = rowptr[node], endp = rowend[node];
        for (int e = beg + slot * 4; e < endp; e += 32) {
            int4 idx = *(const int4*)(csrP + e);
            uint4 r0 = Gch[(size_t)idx.x * 2 + comp];
            uint4 r1 = Gch[(size_t)idx.y * 2 + comp];
            uint4 r2 = Gch[(size_t)idx.z * 2 + comp];
            uint4 r3 = Gch[(size_t)idx.w * 2 + comp];
            bfacc8(a, r0); bfacc8(a, r1); bfacc8(a, r2); bfacc8(a, r3);
        }
    }
#pragma unroll
    for (int m = 2; m < 16; m <<= 1) {
#pragma unroll
        for (int i = 0; i < 8; ++i) a[i] += __shfl_xor(a[i], m);
    }
    if (vn && (lane & 14) == 0) {
        float dv = dinv[node];
        const float* bb = b1 + c * 16 + comp * 8;
        float h[8];
#pragma unroll
        for (int i = 0; i < 8; ++i) {
            float x1 = fmaxf(fmaf(dv, a[i], bb[i]), 0.f);
            h[i] = dv * x1;
        }
        uint4 hp;
        hp.x = f2bf(h[0]) | (f2bf(h[1]) << 16);
        hp.y = f2bf(h[2]) | (f2bf(h[3]) << 16);
        hp.z = f2bf(h[4]) | (f2bf(h[5]) << 16);
        hp.w = f2bf(h[6]) | (f2bf(h[7]) << 16);
        ((uint4*)(Hc + (size_t)c * (nN + 1) * 8))[(size_t)node * 2 + comp] = hp;
    }
}

// ---------- agg2: ILP-4 gather over H chunk, write A2 fp32 [nN][32] ----------
__global__ void __launch_bounds__(256)
agg2v2(const int* __restrict__ rowptr, const int* __restrict__ rowend,
       const int* __restrict__ csrP, const unsigned* __restrict__ Hc,
       const float* __restrict__ dinv, float* __restrict__ A2, int nN, int K) {
    int b = blockIdx.x;
    int xcd = b & 7;
    int c = xcd & 1;
    int k = (b >> 3) * 4 + (xcd >> 1);
    if (k >= K) return;
    int t = threadIdx.x, wv = t >> 6, lane = t & 63;
    int node = k * 16 + wv * 4 + (lane >> 4);
    int slot = (lane >> 1) & 7, comp = lane & 1;
    bool vn = node < nN;
    const uint4* Hch = (const uint4*)(Hc + (size_t)c * (nN + 1) * 8);
    float a[8] = {0, 0, 0, 0, 0, 0, 0, 0};
    if (vn) {
        if ((lane & 14) == 0) bfacc8(a, Hch[(size_t)node * 2 + comp]);  // self-loop
        int beg = rowptr[node], endp = rowend[node];
        for (int e = beg + slot * 4; e < endp; e += 32) {
            int4 idx = *(const int4*)(csrP + e);
            uint4 r0 = Hch[(size_t)idx.x * 2 + comp];
            uint4 r1 = Hch[(size_t)idx.y * 2 + comp];
            uint4 r2 = Hch[(size_t)idx.z * 2 + comp];
            uint4 r3 = Hch[(size_t)idx.w * 2 + comp];
            bfacc8(a, r0); bfacc8(a, r1); bfacc8(a, r2); bfacc8(a, r3);
        }
    }
#pragma unroll
    for (int m = 2; m < 16; m <<= 1) {
#pragma unroll
        for (int i = 0; i < 8; ++i) a[i] += __shfl_xor(a[i], m);
    }
    if (vn && (lane & 14) == 0) {
        float dv = dinv[node];
        float* dst = A2 + (size_t)node * F1 + c * 16 + comp * 8;
        float4 o0 = make_float4(dv * a[0], dv * a[1], dv * a[2], dv * a[3]);
        float4 o1 = make_float4(dv * a[4], dv * a[5], dv * a[6], dv * a[7]);
        ((float4*)dst)[0] = o0;
        ((float4*)dst)[1] = o1;
    }
}

// ---------- segmented pool of x1 from Hc (batch sorted; flush on graph change) ----------
__global__ void __launch_bounds__(256)
poolX1(const unsigned* __restrict__ Hc, const float* __restrict__ rs,
       const int* __restrict__ batch, float* __restrict__ psum, int nN) {
    int t = threadIdx.x, wv = t >> 6, lane = t & 63;
    int c = wv >> 1, half = wv & 1;
    int base = blockIdx.x * PNPB + half * (PNPB / 2);
    int w32 = lane & 7, noff = lane >> 3;
    const unsigned* Hch = Hc + (size_t)c * (nN + 1) * 8;
    int feat = c * 16 + w32 * 2;
    float a0 = 0.f, a1 = 0.f;
    int curG = -1;
#pragma unroll 4
    for (int i = 0; i < PNPB / 16; ++i) {
        int node = base + noff + 8 * i;
        if (node >= nN) break;
        int bg = batch[node];
        if (bg != curG) {
            if (curG >= 0) {
                atomicAdd(&psum[(size_t)curG * FJ + feat + 0], a0);
                atomicAdd(&psum[(size_t)curG * FJ + feat + 1], a1);
            }
            a0 = a1 = 0.f; curG = bg;
        }
        unsigned v = Hch[(size_t)node * 8 + w32];
        float r = rs[node];
        a0 = fmaf(bf2f(v & 0xffffu), r, a0);
        a1 = fmaf(bf2f(v >> 16), r, a1);
    }
    if (curG >= 0) {
        atomicAdd(&psum[(size_t)curG * FJ + feat + 0], a0);
        atomicAdd(&psum[(size_t)curG * FJ + feat + 1], a1);
    }
}

// ---------- segmented x2 pool v2: LDS-staged A2, 16 nodes/wave ----------
__global__ void __launch_bounds__(256)
poolX2(const float* __restrict__ A2, const float* __restrict__ W2,
       const float* __restrict__ b2, const int* __restrict__ batch,
       float* __restrict__ psum, int nN) {
    __shared__ float W2s[F1 * F2];      // 8 KB
    __shared__ float aL[NP2][F1];       // 8 KB
    int t = threadIdx.x;
    for (int i = t; i < F1 * F2; i += 256) W2s[i] = W2[i];
    int nbase = blockIdx.x * NP2;
    {
        const float4* A4 = (const float4*)(A2 + (size_t)nbase * F1);
        float4* aL4 = (float4*)aL;
        int total4 = NP2 * F1 / 4;      // 512
        for (int i = t; i < total4; i += 256) {
            int gnode = nbase + (i >> 3);
            aL4[i] = (gnode < nN) ? A4[i] : make_float4(0.f, 0.f, 0.f, 0.f);
        }
    }
    __syncthreads();
    int wv = t >> 6, lane = t & 63;
    int n0 = wv * (NP2 / 4);
    float bj = b2[lane];
    float acc = 0.f;
    int curG = -1;
    for (int i = 0; i < NP2 / 4; ++i) {
        int node = nbase + n0 + i;
        if (node >= nN) break;
        int bg = batch[node];
        if (bg != curG) {
            if (curG >= 0) atomicAdd(&psum[(size_t)curG * FJ + F1 + lane], acc);
            acc = 0.f; curG = bg;
        }
        const float* a = aL[n0 + i];
        float dot = 0.f;
#pragma unroll
        for (int k = 0; k < F1; ++k) dot = fmaf(a[k], W2s[k * F2 + lane], dot);
        acc += fmaxf(dot + bj, 0.f);
    }
    if (curG >= 0) atomicAdd(&psum[(size_t)curG * FJ + F1 + lane], acc);
}

// ---------- counts via binary search (batch sorted, no atomics) ----------
__global__ void cntBS(const int* __restrict__ batch, float* __restrict__ cnt,
                      int nN, int nG) {
    int g = blockIdx.x * blockDim.x + threadIdx.x;
    if (g >= nG) return;
    int lo = 0, hi = nN;
    while (lo < hi) { int m = (lo + hi) >> 1; if (batch[m] < g) lo = m + 1; else hi = m; }
    int s = lo;
    lo = 0; hi = nN;
    while (lo < hi) { int m = (lo + hi) >> 1; if (batch[m] < g + 1) lo = m + 1; else hi = m; }
    cnt[g] = (float)(lo - s);
}

__global__ void mlp_kernel(const float* __restrict__ psum, const float* __restrict__ cnt,
                           const float* __restrict__ fW1, const float* __restrict__ fb1,
                           const float* __restrict__ fW2, const float* __restrict__ fb2,
                           float* __restrict__ out) {
    __shared__ float p[FJ];
    __shared__ float red[FH];
    int g = blockIdx.x, tid = threadIdx.x;
    float c = fmaxf(cnt[g], 1.0f);
    if (tid < FJ) p[tid] = psum[g * FJ + tid] / c;
    __syncthreads();
    float acc = fb1[tid];
    for (int k = 0; k < FJ; ++k) acc = fmaf(p[k], fW1[k * FH + tid], acc);
    float h = fmaxf(acc, 0.f);
    red[tid] = h * fW2[tid];
    __syncthreads();
    for (int s = FH / 2; s > 0; s >>= 1) {
        if (tid < s) red[tid] += red[tid + s];
        __syncthreads();
    }
    if (tid == 0) out[g] = red[0] + fb2[0];
}

extern "C" void kernel_launch(void* const* d_in, const int* in_sizes, int n_in,
                              void* d_out, int out_size, void* d_ws, size_t ws_size,
                              hipStream_t stream) {
    const float* x   = (const float*)d_in[0];
    const int*   ei  = (const int*)d_in[1];
    const int*   bat = (const int*)d_in[2];
    const float* W1  = (const float*)d_in[3];
    const float* b1  = (const float*)d_in[4];
    const float* W2  = (const float*)d_in[5];
    const float* b2  = (const float*)d_in[6];
    const float* fW1 = (const float*)d_in[7];
    const float* fb1 = (const float*)d_in[8];
    const float* fW2 = (const float*)d_in[9];
    const float* fb2 = (const float*)d_in[10];
    float* out = (float*)d_out;

    int nN = in_sizes[0] / FEAT_IN;
    int nE = in_sizes[1] / 2;
    int nG = out_size;
    const int* src = ei;
    const int* dst = ei + nE;

    int nB  = (nN + BNODES - 1) >> BSH;
    int nCh = (nE + CH - 1) / CH;
    int K   = (nN + 15) / 16;            // 16 nodes per block (4 waves x 4 nodes)
    int gridC = ((K + 3) / 4) * 8;       // XCD-pinned: 8 blocks cover {2 chunks x 4 k}

    char* w = (char*)d_ws;
    auto alloc = [&](size_t bytes) { char* p = w; w += (bytes + 15) & ~(size_t)15; return p; };
    int*      bcnt   = (int*)alloc(NBMAX * 4);
    int*      boff   = (int*)alloc((NBMAX + 1) * 4);
    int*      bcur   = (int*)alloc(NBMAX * 4);
    unsigned* EB     = (unsigned*)alloc((size_t)nE * 4);
    int*      rowptr = (int*)alloc((size_t)nN * 4);
    int*      rowend = (int*)alloc((size_t)nN * 4);
    int*      csrP   = (int*)alloc(((size_t)nE + (size_t)NBMAX * PADMAX + 64) * 4);
    float*    dinv   = (float*)alloc((size_t)nN * 4);
    float*    rsb    = (float*)alloc((size_t)nN * 4);
    unsigned* Gc     = (unsigned*)alloc((size_t)2 * (nN + 1) * 16 * 2);  // bf16 [2][nN+1][16]
    unsigned* Hc     = (unsigned*)alloc((size_t)2 * (nN + 1) * 16 * 2);
    float*    A2     = (float*)alloc((size_t)(nN + NP2) * F1 * 4);
    float*    psum   = (float*)alloc((size_t)nG * FJ * 4);
    float*    cnt    = (float*)alloc((size_t)nG * 4);

    hipMemsetAsync(bcnt, 0, NBMAX * 4, stream);
    hipMemsetAsync(psum, 0, (size_t)nG * FJ * 4, stream);
    // zero sentinel rows (node nN) of each chunk in Gc and Hc
    for (int c = 0; c < 2; ++c) {
        hipMemsetAsync(Gc + ((size_t)c * (nN + 1) + nN) * 16, 0, 32, stream);
        hipMemsetAsync(Hc + ((size_t)c * (nN + 1) + nN) * 16, 0, 32, stream);
    }

    // CSR build (padded) via dst-buckets
    histA<<<1024, 256, 0, stream>>>(dst, bcnt, nE, nB);
    scanBk<<<1, 256, 0, stream>>>(bcnt, boff, bcur, nB, nE);
    scatterEB<<<nCh, 256, 0, stream>>>(src, dst, bcur, EB, nE, nB);
    bucketSortK<<<nB, 256, 0, stream>>>(EB, boff, rowptr, rowend, csrP, dinv, rsb, nN, nB);

    // layer 1
    gemm1v3<<<(nN + GR - 1) / GR, 256, 0, stream>>>((const float4*)x, W1, dinv, Gc, nN);
    agg1v2<<<gridC, 256, 0, stream>>>(rowptr, rowend, csrP, Gc, dinv, b1, Hc, nN, K);
    // layer 2
    agg2v2<<<gridC, 256, 0, stream>>>(rowptr, rowend, csrP, Hc, dinv, A2, nN, K);

    // segmented pooling + counts + MLP
    poolX1<<<(nN + PNPB - 1) / PNPB, 256, 0, stream>>>(Hc, rsb, bat, psum, nN);
    poolX2<<<(nN + NP2 - 1) / NP2, 256, 0, stream>>>(A2, W2, b2, bat, psum, nN);
    cntBS<<<(nG + 255) / 256, 256, 0, stream>>>(bat, cnt, nN, nG);
    mlp_kernel<<<nG, FH, 0, stream>>>(psum, cnt, fW1, fb1, fW2, fb2, out);
}